// Round 8
// baseline (8159.529 us; speedup 1.0000x reference)
//
#include <hip/hip_runtime.h>
#include <math.h>

#define BATCH 32
#define TT    192
#define DM    512
#define CIN   64
#define SEQL  336
#define DFF   2048
#define NH    8
#define COF   0.1f
#define OUTN  (BATCH*TT*CIN)   // 393216

typedef _Float16 h2_t __attribute__((ext_vector_type(2)));
union H2U { unsigned int u; h2_t h; };

typedef short bf16x8 __attribute__((ext_vector_type(8)));
typedef float f32x4 __attribute__((ext_vector_type(4)));

__device__ __forceinline__ unsigned short f2bf(float v) {
  union { float f; unsigned int u; } a; a.f = v;
  unsigned int r = (a.u + 0x7fffu + ((a.u >> 16) & 1u)) >> 16;  // RNE
  return (unsigned short)r;
}

// signed 4x i8 dot product with i32 accumulate
__device__ __forceinline__ int sd4(unsigned int a, unsigned int b, int c) {
#if __has_builtin(__builtin_amdgcn_sdot4)
  return __builtin_amdgcn_sdot4((int)a, (int)b, c, false);
#else
  c += (int)(signed char)(a & 0xff) * (int)(signed char)(b & 0xff);
  c += (int)(signed char)((a >> 8) & 0xff) * (int)(signed char)((b >> 8) & 0xff);
  c += (int)(signed char)((a >> 16) & 0xff) * (int)(signed char)((b >> 16) & 0xff);
  c += (int)(signed char)(a >> 24) * (int)(signed char)(b >> 24);
  return c;
#endif
}

// quantize 4 floats (scale 127/8) into one packed i8x4 word
__device__ __forceinline__ unsigned int packq4(const float* hp) {
  int a = (int)rintf(hp[0] * 15.875f); a = a < -127 ? -127 : (a > 127 ? 127 : a);
  int b = (int)rintf(hp[1] * 15.875f); b = b < -127 ? -127 : (b > 127 ? 127 : b);
  int c = (int)rintf(hp[2] * 15.875f); c = c < -127 ? -127 : (c > 127 ? 127 : c);
  int d = (int)rintf(hp[3] * 15.875f); d = d < -127 ? -127 : (d > 127 ? 127 : d);
  return (unsigned int)((a & 0xff) | ((b & 0xff) << 8) | ((c & 0xff) << 16) |
                        ((d & 0xff) << 24));
}

__device__ __forceinline__ int sd16(uint4 w, uint4 h, int acc) {
  acc = sd4(w.x, h.x, acc); acc = sd4(w.y, h.y, acc);
  acc = sd4(w.z, h.z, acc); acc = sd4(w.w, h.w, acc);
  return acc;
}

// ---------------- small utility kernels ----------------

__global__ void zero_loss_kernel(float* loss) {
  if (threadIdx.x == 0) loss[0] = 0.f;
}

__global__ void zero_flags_kernel(unsigned int* f) { f[threadIdx.x] = 0u; }  // 256 thr

__global__ void finalize_kernel(float* dout, const float* loss) {
  dout[OUTN] = loss[0] * (1.f / (float)OUTN);
}

__global__ void stats_kernel(const float* __restrict__ x, float* __restrict__ means,
                             float* __restrict__ stdev) {
  int b = blockIdx.x, c = threadIdx.x;  // 64 threads
  const float* xb = x + (size_t)b * SEQL * CIN + c;
  float s = 0.f;
  for (int t = 0; t < SEQL; t++) s += xb[t * CIN];
  float mu = s * (1.f / SEQL);
  float s2 = 0.f;
  for (int t = 0; t < SEQL; t++) { float d = xb[t * CIN] - mu; s2 += d * d; }
  means[b * CIN + c] = mu;
  stdev[b * CIN + c] = sqrtf(s2 * (1.f / SEQL) + 1e-5f);
}

__global__ void pl1_kernel(const float* __restrict__ x, const float* __restrict__ means,
                           const float* __restrict__ stdev, const float* __restrict__ w,
                           const float* __restrict__ bias, float* __restrict__ pre) {
  int p = blockIdx.x, b = blockIdx.y, c = threadIdx.x;  // 64 threads
  float mu = means[b * CIN + c];
  float inv = 1.f / stdev[b * CIN + c];
  const float* xb = x + (size_t)b * SEQL * CIN + c;
  const float* wp = w + p * SEQL;
  float acc = 0.f;
  for (int t = 0; t < SEQL; t++) acc += (xb[t * CIN] - mu) * wp[t];
  pre[((size_t)b * TT + p) * CIN + c] = acc * inv + bias[p];
}

__global__ void pl2_kernel(const float* __restrict__ pre, const float* __restrict__ w,
                           const float* __restrict__ bias, float* __restrict__ out) {
  int q = blockIdx.x, b = blockIdx.y, c = threadIdx.x;  // 64 threads
  const float* pb = pre + (size_t)b * TT * CIN + c;
  const float* wq = w + q * TT;
  float acc = 0.f;
  for (int p = 0; p < TT; p++) acc += pb[p * CIN] * wq[p];
  out[((size_t)b * TT + q) * CIN + c] = acc + bias[q];
}

// emb = circular-conv3(corrupt) + pos_emb + mark@tf_w ; also bf16 copy
__global__ void embed_kernel(const float* __restrict__ corrupt, const float* __restrict__ ymark,
                             const float* __restrict__ conv_w, const float* __restrict__ tf_w,
                             float* __restrict__ emb, unsigned short* __restrict__ embB) {
  int t = blockIdx.x, b = blockIdx.y, d = threadIdx.x;  // 512 threads
  __shared__ float xm[CIN], x0[CIN], xp[CIN], mk[4];
  int tm = (t + TT - 1) % TT, tp = (t + 1) % TT;
  if (d < CIN) {
    xm[d] = corrupt[((size_t)b * TT + tm) * CIN + d];
    x0[d] = corrupt[((size_t)b * TT + t) * CIN + d];
    xp[d] = corrupt[((size_t)b * TT + tp) * CIN + d];
  }
  if (d < 4) mk[d] = ymark[((size_t)b * 240 + 48 + t) * 4 + d];
  __syncthreads();
  float acc = 0.f;
  const float* w0 = conv_w + d;
  const float* w1 = conv_w + CIN * DM + d;
  const float* w2 = conv_w + 2 * CIN * DM + d;
  #pragma unroll 8
  for (int c = 0; c < CIN; c++)
    acc += xm[c] * w0[c * DM] + x0[c] * w1[c * DM] + xp[c] * w2[c * DM];
  int i2 = (d >> 1) * 2;
  float freq = expf((float)i2 * (-9.210340371976184f / (float)DM));
  float ang = (float)t * freq;
  float pe = (d & 1) ? cosf(ang) : sinf(ang);
  float mkacc = mk[0] * tf_w[d] + mk[1] * tf_w[DM + d] + mk[2] * tf_w[2 * DM + d] +
                mk[3] * tf_w[3 * DM + d];
  float val = acc + pe + mkacc;
  size_t o = ((size_t)b * TT + t) * DM + d;
  emb[o] = val;
  embB[o] = f2bf(val);
}

// ---------------- fp32 GEMM (kept for proj N=64) ----------------
template <int TB, int RELU>
__global__ __launch_bounds__(256) void gemm_kernel(const float* __restrict__ A,
                                                   const float* __restrict__ B,
                                                   const float* __restrict__ bias,
                                                   float* __restrict__ C, int M, int N, int K) {
  __shared__ float As[16][68];
  __shared__ float Bs[16][68];
  int tid = threadIdx.x;
  int bn = blockIdx.x * 64, bm = blockIdx.y * 64;
  int tx = tid & 15, ty = tid >> 4;
  int row0 = ty * 4, col0 = tx * 4;
  float acc[4][4] = {};
  for (int k0 = 0; k0 < K; k0 += 16) {
    {
      int m = tid >> 2, kq = (tid & 3) << 2;
      float4 av = *(const float4*)&A[(size_t)(bm + m) * K + k0 + kq];
      As[kq + 0][m] = av.x; As[kq + 1][m] = av.y; As[kq + 2][m] = av.z; As[kq + 3][m] = av.w;
    }
    if (TB) {
      int n = tid >> 2, kq = (tid & 3) << 2;
      float4 bv = *(const float4*)&B[(size_t)(bn + n) * K + k0 + kq];
      Bs[kq + 0][n] = bv.x; Bs[kq + 1][n] = bv.y; Bs[kq + 2][n] = bv.z; Bs[kq + 3][n] = bv.w;
    } else {
      int kk = tid >> 4, nq = (tid & 15) << 2;
      float4 bv = *(const float4*)&B[(size_t)(k0 + kk) * N + bn + nq];
      *(float4*)&Bs[kk][nq] = bv;
    }
    __syncthreads();
    #pragma unroll
    for (int k = 0; k < 16; k++) {
      float4 a4 = *(const float4*)&As[k][row0];
      float4 b4 = *(const float4*)&Bs[k][col0];
      float a[4] = {a4.x, a4.y, a4.z, a4.w};
      float bb[4] = {b4.x, b4.y, b4.z, b4.w};
      #pragma unroll
      for (int i = 0; i < 4; i++)
        #pragma unroll
        for (int j = 0; j < 4; j++) acc[i][j] += a[i] * bb[j];
    }
    __syncthreads();
  }
  float bv[4] = {0.f, 0.f, 0.f, 0.f};
  if (bias) *(float4*)bv = *(const float4*)&bias[bn + col0];
  #pragma unroll
  for (int i = 0; i < 4; i++) {
    float ov[4];
    #pragma unroll
    for (int j = 0; j < 4; j++) {
      float v = acc[i][j] + bv[j];
      if (RELU) v = fmaxf(v, 0.f);
      ov[j] = v;
    }
    *(float4*)&C[(size_t)(bm + row0 + i) * N + bn + col0] = *(float4*)ov;
  }
}

// ---------------- bf16 MFMA GEMM (bf16 A, bf16 Bt [N][K]) ----------------
template <int RELU, int WF32, int WBF16, int AXPY>
__global__ __launch_bounds__(256) void gemm_bf16_kernel(
    const unsigned short* __restrict__ A, const unsigned short* __restrict__ Bt,
    const float* __restrict__ bias, float* __restrict__ C, unsigned short* __restrict__ Cb,
    const float* __restrict__ R, const float* __restrict__ alphaPtr, int M, int N, int K) {
  __shared__ __align__(16) unsigned short As[128 * 40];
  __shared__ __align__(16) unsigned short Bs[128 * 40];
  int tid = threadIdx.x;
  int bm = blockIdx.y * 128, bn = blockIdx.x * 128;
  int wave = tid >> 6, lane = tid & 63;
  int wm = (wave >> 1) * 64, wn = (wave & 1) * 64;
  int r15 = lane & 15, q = lane >> 4;
  f32x4 acc[4][4] = {};
  int sr = tid >> 1, sh = (tid & 1) * 16;
  for (int k0 = 0; k0 < K; k0 += 32) {
    {
      const unsigned short* ap = &A[(size_t)(bm + sr) * K + k0 + sh];
      *(uint4*)&As[sr * 40 + sh] = *(const uint4*)ap;
      *(uint4*)&As[sr * 40 + sh + 8] = *(const uint4*)(ap + 8);
    }
    {
      const unsigned short* bp = &Bt[(size_t)(bn + sr) * K + k0 + sh];
      *(uint4*)&Bs[sr * 40 + sh] = *(const uint4*)bp;
      *(uint4*)&Bs[sr * 40 + sh + 8] = *(const uint4*)(bp + 8);
    }
    __syncthreads();
    bf16x8 af[4], bfr[4];
    #pragma unroll
    for (int mi = 0; mi < 4; mi++)
      af[mi] = *(const bf16x8*)&As[(wm + mi * 16 + r15) * 40 + q * 8];
    #pragma unroll
    for (int ni = 0; ni < 4; ni++)
      bfr[ni] = *(const bf16x8*)&Bs[(wn + ni * 16 + r15) * 40 + q * 8];
    #pragma unroll
    for (int mi = 0; mi < 4; mi++)
      #pragma unroll
      for (int ni = 0; ni < 4; ni++)
        acc[mi][ni] =
            __builtin_amdgcn_mfma_f32_16x16x32_bf16(af[mi], bfr[ni], acc[mi][ni], 0, 0, 0);
    __syncthreads();
  }
  float al = AXPY ? alphaPtr[0] : 0.f;
  #pragma unroll
  for (int mi = 0; mi < 4; mi++) {
    #pragma unroll
    for (int ni = 0; ni < 4; ni++) {
      int col = bn + wn + ni * 16 + r15;
      float bv = (bias && !AXPY) ? bias[col] : 0.f;
      #pragma unroll
      for (int v = 0; v < 4; v++) {
        int row = bm + wm + mi * 16 + q * 4 + v;
        float val = acc[mi][ni][v] + bv;
        if (RELU) val = fmaxf(val, 0.f);
        if (WF32) C[(size_t)row * N + col] = val;
        if (WBF16) Cb[(size_t)row * N + col] = f2bf(val);
        if (AXPY) {
          if (col < 64)
            C[(size_t)row * 64 + col] = R[(size_t)row * 64 + col] - al * val;
        }
      }
    }
  }
}

// pack transpose: dst[n*K + k] = bf16(src[k*N + n])
__global__ void pack_transpose_bf16_kernel(const float* __restrict__ src,
                                           unsigned short* __restrict__ dst, int K, int N) {
  int idx = blockIdx.x * 256 + threadIdx.x;
  int k = idx % K, n = idx / K;
  dst[idx] = f2bf(src[(size_t)k * N + n]);
}

__global__ void pack_bf16_kernel(const float* __restrict__ src, unsigned short* __restrict__ dst,
                                 int n) {
  int idx = blockIdx.x * 256 + threadIdx.x;
  if (idx < n) dst[idx] = f2bf(src[idx]);
}

// WxProjB[n][k] (n<128, k<1536) = n<64 ? bf16(wih[k*128 + n]) : 0
__global__ void pack_wxproj_kernel(const float* __restrict__ wih,
                                   unsigned short* __restrict__ dst) {
  int idx = blockIdx.x * 256 + threadIdx.x;  // 128*1536
  int k = idx % 1536, n = idx / 1536;
  float v = (n < 64) ? wih[(size_t)k * 128 + n] : 0.f;
  dst[idx] = f2bf(v);
}

__global__ void concat_qkv_bias_kernel(const float* __restrict__ bq, const float* __restrict__ bk,
                                       const float* __restrict__ bv, float* __restrict__ dst) {
  int l = blockIdx.y;
  int i = blockIdx.x * 256 + threadIdx.x;  // < 1536
  float v = (i < 512) ? bq[l * 512 + i]
                      : ((i < 1024) ? bk[l * 512 + i - 512] : bv[l * 512 + i - 1024]);
  dst[l * 1536 + i] = v;
}

// ---------------- MFMA attention: one block per (h,b) ----------------
__global__ __launch_bounds__(256) void attention_mfma_kernel(
    const unsigned short* __restrict__ qkv, unsigned short* __restrict__ attnO) {
  __shared__ __align__(16) unsigned short Ks[192 * 72];
  __shared__ __align__(16) unsigned short Vt[64 * 200];
  __shared__ __align__(16) float Ps[4][16 * 36];
  int h = blockIdx.x, b = blockIdx.y;
  int tid = threadIdx.x, wave = tid >> 6, lane = tid & 63;
  int m = lane & 15, q = lane >> 4;
  const unsigned short* Qg = qkv + (size_t)b * TT * 1536 + h * 64;
  const unsigned short* Kg = Qg + 512;
  const unsigned short* Vg = Qg + 1024;
  for (int idx = tid; idx < 192 * 8; idx += 256) {
    int s = idx >> 3, ch = (idx & 7) * 8;
    *(uint4*)&Ks[s * 72 + ch] = *(const uint4*)&Kg[(size_t)s * 1536 + ch];
  }
  for (int idx = tid; idx < 96 * 8; idx += 256) {
    int sp = idx >> 3, co = (idx & 7) * 8;
    uint4 v0 = *(const uint4*)&Vg[(size_t)(2 * sp) * 1536 + co];
    uint4 v1 = *(const uint4*)&Vg[(size_t)(2 * sp + 1) * 1536 + co];
    const unsigned short* e0 = (const unsigned short*)&v0;
    const unsigned short* e1 = (const unsigned short*)&v1;
    unsigned int* vtw = (unsigned int*)Vt;
    #pragma unroll
    for (int u = 0; u < 8; u++)
      vtw[(co + u) * 100 + sp] = (unsigned int)e0[u] | ((unsigned int)e1[u] << 16);
  }
  __syncthreads();
  float* ps = Ps[wave];
  for (int tile = wave; tile < 12; tile += 4) {
    int t0 = tile * 16;
    bf16x8 qf0 = *(const bf16x8*)&Qg[(size_t)(t0 + m) * 1536 + q * 8];
    bf16x8 qf1 = *(const bf16x8*)&Qg[(size_t)(t0 + m) * 1536 + 32 + q * 8];
    f32x4 S[12];
    #pragma unroll
    for (int nt = 0; nt < 12; nt++) {
      bf16x8 kf0 = *(const bf16x8*)&Ks[(nt * 16 + m) * 72 + q * 8];
      bf16x8 kf1 = *(const bf16x8*)&Ks[(nt * 16 + m) * 72 + 32 + q * 8];
      f32x4 a = {0.f, 0.f, 0.f, 0.f};
      a = __builtin_amdgcn_mfma_f32_16x16x32_bf16(qf0, kf0, a, 0, 0, 0);
      a = __builtin_amdgcn_mfma_f32_16x16x32_bf16(qf1, kf1, a, 0, 0, 0);
      S[nt] = a;
    }
    float mx[4] = {-1e30f, -1e30f, -1e30f, -1e30f};
    #pragma unroll
    for (int nt = 0; nt < 12; nt++)
      #pragma unroll
      for (int v = 0; v < 4; v++) {
        S[nt][v] *= 0.125f;
        mx[v] = fmaxf(mx[v], S[nt][v]);
      }
    #pragma unroll
    for (int d = 1; d < 16; d <<= 1) {
      #pragma unroll
      for (int v = 0; v < 4; v++) mx[v] = fmaxf(mx[v], __shfl_xor(mx[v], d));
    }
    float sm[4] = {0.f, 0.f, 0.f, 0.f};
    #pragma unroll
    for (int nt = 0; nt < 12; nt++)
      #pragma unroll
      for (int v = 0; v < 4; v++) {
        float e = __expf(S[nt][v] - mx[v]);
        S[nt][v] = e;
        sm[v] += e;
      }
    #pragma unroll
    for (int d = 1; d < 16; d <<= 1) {
      #pragma unroll
      for (int v = 0; v < 4; v++) sm[v] += __shfl_xor(sm[v], d);
    }
    float inv[4];
    #pragma unroll
    for (int v = 0; v < 4; v++) inv[v] = 1.f / sm[v];
    f32x4 o[4] = {};
    for (int kc = 0; kc < 6; kc++) {
      asm volatile("s_waitcnt lgkmcnt(0)" ::: "memory");
      #pragma unroll
      for (int half = 0; half < 2; half++) {
        int nt = 2 * kc + half;
        #pragma unroll
        for (int v = 0; v < 4; v++) ps[(q * 4 + v) * 36 + half * 16 + m] = S[nt][v];
      }
      asm volatile("s_waitcnt lgkmcnt(0)" ::: "memory");
      float4 p0 = *(const float4*)&ps[m * 36 + q * 8];
      float4 p1 = *(const float4*)&ps[m * 36 + q * 8 + 4];
      unsigned short tmp[8];
      tmp[0] = f2bf(p0.x); tmp[1] = f2bf(p0.y); tmp[2] = f2bf(p0.z); tmp[3] = f2bf(p0.w);
      tmp[4] = f2bf(p1.x); tmp[5] = f2bf(p1.y); tmp[6] = f2bf(p1.z); tmp[7] = f2bf(p1.w);
      bf16x8 pf = *(bf16x8*)tmp;
      #pragma unroll
      for (int nt2 = 0; nt2 < 4; nt2++) {
        bf16x8 vf = *(const bf16x8*)&Vt[(nt2 * 16 + m) * 200 + kc * 32 + q * 8];
        o[nt2] = __builtin_amdgcn_mfma_f32_16x16x32_bf16(pf, vf, o[nt2], 0, 0, 0);
      }
    }
    #pragma unroll
    for (int nt2 = 0; nt2 < 4; nt2++)
      #pragma unroll
      for (int v = 0; v < 4; v++) {
        size_t row = (size_t)b * TT + t0 + q * 4 + v;
        attnO[row * 512 + h * 64 + nt2 * 16 + m] = f2bf(o[nt2][v] * inv[v]);
      }
  }
}

// ---------------- layernorm with residual, in-place on x; bf16 copy ----------------
__global__ __launch_bounds__(256) void ln_residual_kernel(float* __restrict__ x,
                                                          const float* __restrict__ res,
                                                          const float* __restrict__ g,
                                                          const float* __restrict__ b,
                                                          unsigned short* __restrict__ xb) {
  int row = blockIdx.x, tid = threadIdx.x;
  __shared__ float red[256];
  float* xr = x + (size_t)row * DM;
  const float* rr = res + (size_t)row * DM;
  float v0 = xr[tid] + rr[tid];
  float v1 = xr[tid + 256] + rr[tid + 256];
  red[tid] = v0 + v1;
  __syncthreads();
  for (int s = 128; s > 0; s >>= 1) {
    if (tid < s) red[tid] += red[tid + s];
    __syncthreads();
  }
  float mu = red[0] * (1.f / DM);
  __syncthreads();
  float d0 = v0 - mu, d1 = v1 - mu;
  red[tid] = d0 * d0 + d1 * d1;
  __syncthreads();
  for (int s = 128; s > 0; s >>= 1) {
    if (tid < s) red[tid] += red[tid + s];
    __syncthreads();
  }
  float rstd = rsqrtf(red[0] * (1.f / DM) + 1e-5f);
  float o0 = d0 * rstd * g[tid] + b[tid];
  float o1 = d1 * rstd * g[tid + 256] + b[tid + 256];
  xr[tid] = o0;
  xr[tid + 256] = o1;
  xb[(size_t)row * DM + tid] = f2bf(o0);
  xb[(size_t)row * DM + tid + 256] = f2bf(o1);
}

__global__ void xcat_kernel(const float* __restrict__ corrupt, const float* __restrict__ cond,
                            unsigned short* __restrict__ xcatB) {
  int r = blockIdx.x, tid = threadIdx.x;  // 128 threads
  float v = (tid < 64) ? corrupt[(size_t)r * 64 + tid] : cond[(size_t)r * 64 + (tid - 64)];
  xcatB[(size_t)r * 128 + tid] = f2bf(v);
}

// ---------------- whh i8 pack, oct-split layout ----------------
// per oct (j>>6): entry idx = ((c*2+u)*3+g)*64 + jl ; k = c*32+u*16+m
__global__ void pack_whh_q8_kernel(const float* __restrict__ whh, signed char* __restrict__ whhJ,
                                   float* __restrict__ sws) {
  int row = blockIdx.x;   // 0..1535 = g*512 + j
  int lane = threadIdx.x; // 64
  const float* src = whh + (size_t)row * 512;
  float mx = 0.f;
  for (int k = lane; k < 512; k += 64) mx = fmaxf(mx, fabsf(src[k]));
  for (int off = 32; off > 0; off >>= 1) mx = fmaxf(mx, __shfl_xor(mx, off));
  float inv = (mx > 0.f) ? 127.f / mx : 0.f;
  if (lane == 0) sws[row] = (mx / 127.f) * (8.f / 127.f);
  int g = row >> 9, j = row & 511;
  int oct = j >> 6, jl = j & 63;
  for (int k = lane; k < 512; k += 64) {
    int qv = (int)rintf(src[k] * inv);
    qv = qv < -127 ? -127 : (qv > 127 ? 127 : qv);
    int c = k >> 5, u = (k >> 4) & 1, m = k & 15;
    whhJ[(size_t)oct * 98304 + ((size_t)(((c * 2 + u) * 3 + g) * 64 + jl) << 4) + m] =
        (signed char)qv;
  }
}

// ---------------- Langevin scan: 8 blocks per batch (oct-split), LDS-resident half ----------------
// grid (BATCH, 8), 1024 thr. h-quarters exchanged via agent-scope atomics (same XCD under
// round-robin dispatch: partners b, b+32, ... are congruent mod 8).
__global__ __launch_bounds__(1024) void langevin_scan_kernel(
    const float* __restrict__ gi_all, const float* __restrict__ hx0,
    const signed char* __restrict__ whhJ, const float* __restrict__ sws,
    const float* __restrict__ bhh, const float* __restrict__ score_w,
    unsigned short* __restrict__ dgiB, unsigned int* __restrict__ hqg,
    unsigned int* __restrict__ flags) {
  int b = blockIdx.x, oct = blockIdx.y;
  int tid = threadIdx.x;
  __shared__ __align__(16) uint4 wLDS[3072];   // 48 KB: chunks c<8
  __shared__ int prI[1024], pzI[1024], pnI[1024];
  __shared__ __align__(16) unsigned int hq8[128];
  int jl = tid & 63, c = tid >> 6;  // c == wave id (16 waves)
  int j = oct * 64 + jl;
  const uint4* wslice = (const uint4*)whhJ + (size_t)oct * 6144;
  // stage lower half of weights into LDS
  for (int idx = tid; idx < 3072; idx += 1024) wLDS[idx] = wslice[idx];
  float bhr = 0.f, bhz = 0.f, bhn = 0.f, sw = 0.f, swr = 0.f, swz = 0.f, swn = 0.f;
  float h_cur = 0.f;
  if (tid < 64) {
    bhr = bhh[j]; bhz = bhh[512 + j]; bhn = bhh[1024 + j];
    sw = score_w[j] * COF;
    swr = sws[j]; swz = sws[512 + j]; swn = sws[1024 + j];
    h_cur = hx0[(size_t)b * 512 + j];
  }
  if (tid < 128) {
    float4 hv = *(const float4*)&hx0[(size_t)b * 512 + tid * 4];
    float tmp[4] = {hv.x, hv.y, hv.z, hv.w};
    hq8[tid] = packq4(tmp);
  }
  __syncthreads();
  int base = c * 384 + jl;
  for (int t = 0; t < TT; t++) {
    uint4 hq0 = *(const uint4*)&hq8[c * 8];
    uint4 hq1 = *(const uint4*)&hq8[c * 8 + 4];
    int ir = 0, iz = 0, in_ = 0;
    if (c < 8) {
      ir = sd16(wLDS[base], hq0, ir);        iz = sd16(wLDS[base + 64], hq0, iz);
      in_ = sd16(wLDS[base + 128], hq0, in_);
      ir = sd16(wLDS[base + 192], hq1, ir);  iz = sd16(wLDS[base + 256], hq1, iz);
      in_ = sd16(wLDS[base + 320], hq1, in_);
    } else {
      const uint4* wp = wslice + base;
      ir = sd16(wp[0], hq0, ir);        iz = sd16(wp[64], hq0, iz);
      in_ = sd16(wp[128], hq0, in_);
      ir = sd16(wp[192], hq1, ir);      iz = sd16(wp[256], hq1, iz);
      in_ = sd16(wp[320], hq1, in_);
    }
    prI[tid] = ir; pzI[tid] = iz; pnI[tid] = in_;
    __syncthreads();  // B1: partials ready; all hq8 reads done
    int slot = t & 1;
    if (tid < 64) {
      int sr_ = 0, sz_ = 0, sn_ = 0;
      #pragma unroll
      for (int kk = 0; kk < 16; kk++) {
        sr_ += prI[kk * 64 + jl];
        sz_ += pzI[kk * 64 + jl];
        sn_ += pnI[kk * 64 + jl];
      }
      float gr = (float)sr_ * swr, gz = (float)sz_ * swz, gn = (float)sn_ * swn;
      const float* gi = &gi_all[((size_t)b * TT + t) * 1536];
      float gir = gi[j], giz = gi[512 + j], gin = gi[1024 + j];
      float r = 1.f / (1.f + expf(-(gir + gr + bhr)));
      float z = 1.f / (1.f + expf(-(giz + gz + bhz)));
      float hnv = gn + bhn;
      float hj = h_cur;
      float n = tanhf(gin + r * hnv);
      float dinn = sw * (1.f - z) * (1.f - n * n);
      float dgr = dinn * hnv * r * (1.f - r);
      float dgz = sw * (hj - n) * z * (1.f - z);
      float h_new = (1.f - z) * n + z * hj;
      h_cur = h_new;
      if (t + 1 < TT) {
        // pack own 16 words via shuffle (wave 0 only) and publish
        float v0 = __shfl(h_new, jl * 4);
        float v1 = __shfl(h_new, jl * 4 + 1);
        float v2 = __shfl(h_new, jl * 4 + 2);
        float v3 = __shfl(h_new, jl * 4 + 3);
        if (jl < 16) {
          float tmp[4] = {v0, v1, v2, v3};
          unsigned int wv = packq4(tmp);
          hq8[oct * 16 + jl] = wv;
          __hip_atomic_store(&hqg[(((size_t)slot * BATCH + b) * 8 + oct) * 16 + jl], wv,
                             __ATOMIC_RELAXED, __HIP_MEMORY_SCOPE_AGENT);
        }
        if (jl == 0)
          __hip_atomic_store(&flags[b * 8 + oct], (unsigned)(t + 1), __ATOMIC_RELEASE,
                             __HIP_MEMORY_SCOPE_AGENT);
      }
      // dgi stores AFTER flag release (hidden behind partners' sync latency)
      size_t drow = ((size_t)b * TT + t) * 1536;
      dgiB[drow + j] = f2bf(dgr);
      dgiB[drow + 512 + j] = f2bf(dgz);
      dgiB[drow + 1024 + j] = f2bf(dinn);
    } else if (t + 1 < TT && tid >= 64 && tid < 176) {
      // 112 loader threads: each polls its partner's flag then pulls one word
      int p = (tid - 64) >> 4, w = (tid - 64) & 15;
      int oq = (oct + 1 + p) & 7;
      while (__hip_atomic_load(&flags[b * 8 + oq], __ATOMIC_ACQUIRE,
                               __HIP_MEMORY_SCOPE_AGENT) < (unsigned)(t + 1)) {
        __builtin_amdgcn_s_sleep(2);
      }
      hq8[oq * 16 + w] =
          __hip_atomic_load(&hqg[(((size_t)slot * BATCH + b) * 8 + oq) * 16 + w],
                            __ATOMIC_RELAXED, __HIP_MEMORY_SCOPE_AGENT);
    }
    __syncthreads();  // B2: hq8 complete for next step
  }
}

// denorm + write d_out + loss partial
__global__ __launch_bounds__(256) void denorm_loss_kernel(
    const float* __restrict__ outb, const float* __restrict__ stdev,
    const float* __restrict__ means, const float* __restrict__ y, float* __restrict__ dout,
    float* __restrict__ loss) {
  int idx = blockIdx.x * 256 + threadIdx.x;
  int tid = threadIdx.x;
  int c = idx & 63;
  int bt = idx >> 6;
  int t = bt % TT, b = bt / TT;
  float od = outb[idx] * stdev[b * CIN + c] + means[b * CIN + c];
  dout[idx] = od;
  float diff = fabsf(od - y[((size_t)b * 240 + 48 + t) * CIN + c]);
  __shared__ float red[256];
  red[tid] = diff;
  __syncthreads();
  for (int s = 128; s > 0; s >>= 1) {
    if (tid < s) red[tid] += red[tid + s];
    __syncthreads();
  }
  if (tid == 0) atomicAdd(loss, red[0]);
}

// ---------------- host launch ----------------
extern "C" void kernel_launch(void* const* d_in, const int* in_sizes, int n_in, void* d_out,
                              int out_size, void* d_ws, size_t ws_size, hipStream_t stream) {
  const float* x_enc = (const float*)d_in[0];
  const float* batch_y = (const float*)d_in[2];
  const float* y_mark = (const float*)d_in[3];
  const float* hx_init = (const float*)d_in[4];
  const float* conv_w = (const float*)d_in[5];
  const float* tf_w = (const float*)d_in[6];
  const float* Wq = (const float*)d_in[7];
  const float* Wk = (const float*)d_in[8];
  const float* Wv = (const float*)d_in[9];
  const float* Wo = (const float*)d_in[10];
  const float* bq = (const float*)d_in[11];
  const float* bk = (const float*)d_in[12];
  const float* bv = (const float*)d_in[13];
  const float* bo = (const float*)d_in[14];
  const float* ln1_g = (const float*)d_in[15];
  const float* ln1_b = (const float*)d_in[16];
  const float* W1 = (const float*)d_in[17];
  const float* b1 = (const float*)d_in[18];
  const float* W2 = (const float*)d_in[19];
  const float* b2 = (const float*)d_in[20];
  const float* ln2_g = (const float*)d_in[21];
  const float* ln2_b = (const float*)d_in[22];
  const float* pl1_w = (const float*)d_in[23];
  const float* pl1_b = (const float*)d_in[24];
  const float* pl2_w = (const float*)d_in[25];
  const float* pl2_b = (const float*)d_in[26];
  const float* proj_w = (const float*)d_in[27];
  const float* proj_b = (const float*)d_in[28];
  const float* gru_wih = (const float*)d_in[29];
  const float* gru_whh = (const float*)d_in[30];
  const float* gru_bih = (const float*)d_in[31];
  const float* gru_bhh = (const float*)d_in[32];
  const float* score_w = (const float*)d_in[33];
  const float* alpha = (const float*)d_in[34];
  float* dout = (float*)d_out;

  float* W = (float*)d_ws;
  size_t off = 0;
  float* means = W + off;   off += 2048;
  float* stdev = W + off;   off += 2048;
  float* lossacc = W + off; off += 64;
  float* preA = W + off;    off += (size_t)OUTN;
  float* outA = W + off;    off += (size_t)OUTN;
  float* outB = W + off;    off += (size_t)OUTN;
  float* corrupt = W + off; off += (size_t)OUTN;
  float* cond = W + off;    off += (size_t)OUTN;
  signed char* whhJ = (signed char*)(W + off); off += 786432 / 4;
  float* sws = W + off;     off += 1536;
  unsigned int* flagsU = (unsigned int*)(W + off); off += 256;
  unsigned int* hqg = (unsigned int*)(W + off);    off += 2 * BATCH * 8 * 16;
  float* emb = W + off;     off += (size_t)BATCH * TT * DM;
  float* Kb = W + off;      off += (size_t)BATCH * TT * DM;
  float* gi_all = W + off;  off += (size_t)BATCH * TT * 1536;
  unsigned short* embB = (unsigned short*)(W + off);  off += (size_t)BATCH * TT * DM / 2;
  unsigned short* qkvB = (unsigned short*)(W + off);  off += (size_t)BATCH * TT * 1536 / 2;
  unsigned short* attnOB = (unsigned short*)(W + off); off += (size_t)BATCH * TT * DM / 2;
  unsigned short* FFbB = (unsigned short*)(W + off);  off += (size_t)BATCH * TT * DFF / 2;
  unsigned short* xcatB = (unsigned short*)(W + off); off += (size_t)BATCH * TT * 128 / 2;
  float* bqkv = W + off;    off += 2 * 1536;
  unsigned short* WxProjB = (unsigned short*)(W + off); off += (size_t)128 * 1536 / 2;
  unsigned short* wT = (unsigned short*)(W + off);
  const size_t SQ = (size_t)DM * DM;
  const size_t SFF = (size_t)DM * DFF;
  const size_t LAYER = 4 * SQ + 2 * SFF;
  unsigned short* wihB = wT + 2 * LAYER;
  off += (2 * LAYER + (size_t)1536 * 128) / 2 + 64;
  unsigned short* dgiB = qkvB;  // alias: qkvB dead after attention, reused for dgi

  const int M = BATCH * TT;  // 6144

  zero_loss_kernel<<<1, 64, 0, stream>>>(lossacc);
  stats_kernel<<<BATCH, 64, 0, stream>>>(x_enc, means, stdev);
  pl1_kernel<<<dim3(TT, BATCH), 64, 0, stream>>>(x_enc, means, stdev, pl1_w, pl1_b, preA);
  pack_whh_q8_kernel<<<1536, 64, 0, stream>>>(gru_whh, whhJ, sws);
  pack_wxproj_kernel<<<(128 * 1536) / 256, 256, 0, stream>>>(gru_wih, WxProjB);
  concat_qkv_bias_kernel<<<dim3(6, 2), 256, 0, stream>>>(bq, bk, bv, bqkv);
  for (int l = 0; l < 2; l++) {
    unsigned short* base = wT + (size_t)l * LAYER;
    pack_transpose_bf16_kernel<<<SQ / 256, 256, 0, stream>>>(Wq + (size_t)l * SQ, base, DM, DM);
    pack_transpose_bf16_kernel<<<SQ / 256, 256, 0, stream>>>(Wk + (size_t)l * SQ, base + SQ, DM, DM);
    pack_transpose_bf16_kernel<<<SQ / 256, 256, 0, stream>>>(Wv + (size_t)l * SQ, base + 2 * SQ, DM, DM);
    pack_transpose_bf16_kernel<<<SQ / 256, 256, 0, stream>>>(Wo + (size_t)l * SQ, base + 3 * SQ, DM, DM);
    pack_transpose_bf16_kernel<<<SFF / 256, 256, 0, stream>>>(W1 + (size_t)l * SFF, base + 4 * SQ, DM, DFF);
    pack_transpose_bf16_kernel<<<SFF / 256, 256, 0, stream>>>(W2 + (size_t)l * SFF, base + 4 * SQ + SFF, DFF, DM);
  }
  pack_bf16_kernel<<<(1536 * 128) / 256, 256, 0, stream>>>(gru_wih, wihB, 1536 * 128);

  const float* pre = preA;
  float* outs[2] = {outA, outB};
  for (int s = 0; s < 2; s++) {
    pl2_kernel<<<dim3(TT, BATCH), 64, 0, stream>>>(pre, pl2_w, pl2_b, corrupt);
    embed_kernel<<<dim3(TT, BATCH), DM, 0, stream>>>(corrupt, y_mark, conv_w, tf_w, emb, embB);
    for (int l = 0; l < 2; l++) {
      unsigned short* base = wT + (size_t)l * LAYER;
      gemm_bf16_kernel<0, 0, 1, 0><<<dim3(1536 / 128, M / 128), 256, 0, stream>>>(
          embB, base, bqkv + l * 1536, nullptr, qkvB, nullptr, nullptr, M, 1536, DM);
      attention_mfma_kernel<<<dim3(NH, BATCH), 256, 0, stream>>>(qkvB, attnOB);
      gemm_bf16_kernel<0, 1, 0, 0><<<dim3(DM / 128, M / 128), 256, 0, stream>>>(
          attnOB, base + 3 * SQ, bo + l * DM, Kb, nullptr, nullptr, nullptr, M, DM, DM);
      ln_residual_kernel<<<M, 256, 0, stream>>>(emb, Kb, ln1_g + l * DM, ln1_b + l * DM, embB);
      gemm_bf16_kernel<1, 0, 1, 0><<<dim3(DFF / 128, M / 128), 256, 0, stream>>>(
          embB, base + 4 * SQ, b1 + l * DFF, nullptr, FFbB, nullptr, nullptr, M, DFF, DM);
      gemm_bf16_kernel<0, 1, 0, 0><<<dim3(DM / 128, M / 128), 256, 0, stream>>>(
          FFbB, base + 4 * SQ + SFF, b2 + l * DM, Kb, nullptr, nullptr, nullptr, M, DM, DFF);
      ln_residual_kernel<<<M, 256, 0, stream>>>(emb, Kb, ln2_g + l * DM, ln2_b + l * DM, embB);
    }
    gemm_kernel<1, 0><<<dim3(CIN / 64, M / 64), 256, 0, stream>>>(
        emb, proj_w, proj_b, cond, M, CIN, DM);
    xcat_kernel<<<M, 128, 0, stream>>>(corrupt, cond, xcatB);
    gemm_bf16_kernel<0, 1, 0, 0><<<dim3(1536 / 128, M / 128), 256, 0, stream>>>(
        xcatB, wihB, gru_bih, gi_all, nullptr, nullptr, nullptr, M, 1536, 128);
    zero_flags_kernel<<<1, 256, 0, stream>>>(flagsU);
    langevin_scan_kernel<<<dim3(BATCH, 8), 1024, 0, stream>>>(
        gi_all, hx_init + (size_t)s * BATCH * DM, whhJ, sws, gru_bhh, score_w, dgiB, hqg,
        flagsU);
    // out = xi - alpha * dgi @ Wx^T   (AXPY epilogue)
    gemm_bf16_kernel<0, 0, 0, 1><<<dim3(1, M / 128), 256, 0, stream>>>(
        dgiB, WxProjB, nullptr, outs[s], nullptr, corrupt, alpha, M, 128, 1536);
    denorm_loss_kernel<<<OUTN / 256, 256, 0, stream>>>(outs[s], stdev, means, batch_y, dout,
                                                       lossacc);
    pre = outs[s];
  }
  finalize_kernel<<<1, 1, 0, stream>>>(dout, lossacc);
}

// Round 9
// 2711.786 us; speedup vs baseline: 3.0089x; 3.0089x over previous
//
#include <hip/hip_runtime.h>
#include <math.h>

#define BATCH 32
#define TT    192
#define DM    512
#define CIN   64
#define SEQL  336
#define DFF   2048
#define NH    8
#define COF   0.1f
#define OUTN  (BATCH*TT*CIN)   // 393216

typedef _Float16 h2_t __attribute__((ext_vector_type(2)));
union H2U { unsigned int u; h2_t h; };

typedef short bf16x8 __attribute__((ext_vector_type(8)));
typedef float f32x4 __attribute__((ext_vector_type(4)));

__device__ __forceinline__ unsigned short f2bf(float v) {
  union { float f; unsigned int u; } a; a.f = v;
  unsigned int r = (a.u + 0x7fffu + ((a.u >> 16) & 1u)) >> 16;  // RNE
  return (unsigned short)r;
}

// signed 4x i8 dot product with i32 accumulate
__device__ __forceinline__ int sd4(unsigned int a, unsigned int b, int c) {
#if __has_builtin(__builtin_amdgcn_sdot4)
  return __builtin_amdgcn_sdot4((int)a, (int)b, c, false);
#else
  c += (int)(signed char)(a & 0xff) * (int)(signed char)(b & 0xff);
  c += (int)(signed char)((a >> 8) & 0xff) * (int)(signed char)((b >> 8) & 0xff);
  c += (int)(signed char)((a >> 16) & 0xff) * (int)(signed char)((b >> 16) & 0xff);
  c += (int)(signed char)(a >> 24) * (int)(signed char)(b >> 24);
  return c;
#endif
}

// quantize 4 floats (scale 127/8) into one packed i8x4 word
__device__ __forceinline__ unsigned int packq4(const float* hp) {
  int a = (int)rintf(hp[0] * 15.875f); a = a < -127 ? -127 : (a > 127 ? 127 : a);
  int b = (int)rintf(hp[1] * 15.875f); b = b < -127 ? -127 : (b > 127 ? 127 : b);
  int c = (int)rintf(hp[2] * 15.875f); c = c < -127 ? -127 : (c > 127 ? 127 : c);
  int d = (int)rintf(hp[3] * 15.875f); d = d < -127 ? -127 : (d > 127 ? 127 : d);
  return (unsigned int)((a & 0xff) | ((b & 0xff) << 8) | ((c & 0xff) << 16) |
                        ((d & 0xff) << 24));
}

// ---------------- small utility kernels ----------------

__global__ void zero_loss_kernel(float* loss) {
  if (threadIdx.x == 0) loss[0] = 0.f;
}

__global__ void zero_flags_kernel(unsigned int* f) { f[threadIdx.x] = 0u; }  // 128 thr

__global__ void finalize_kernel(float* dout, const float* loss) {
  dout[OUTN] = loss[0] * (1.f / (float)OUTN);
}

__global__ void stats_kernel(const float* __restrict__ x, float* __restrict__ means,
                             float* __restrict__ stdev) {
  int b = blockIdx.x, c = threadIdx.x;  // 64 threads
  const float* xb = x + (size_t)b * SEQL * CIN + c;
  float s = 0.f;
  for (int t = 0; t < SEQL; t++) s += xb[t * CIN];
  float mu = s * (1.f / SEQL);
  float s2 = 0.f;
  for (int t = 0; t < SEQL; t++) { float d = xb[t * CIN] - mu; s2 += d * d; }
  means[b * CIN + c] = mu;
  stdev[b * CIN + c] = sqrtf(s2 * (1.f / SEQL) + 1e-5f);
}

__global__ void pl1_kernel(const float* __restrict__ x, const float* __restrict__ means,
                           const float* __restrict__ stdev, const float* __restrict__ w,
                           const float* __restrict__ bias, float* __restrict__ pre) {
  int p = blockIdx.x, b = blockIdx.y, c = threadIdx.x;  // 64 threads
  float mu = means[b * CIN + c];
  float inv = 1.f / stdev[b * CIN + c];
  const float* xb = x + (size_t)b * SEQL * CIN + c;
  const float* wp = w + p * SEQL;
  float acc = 0.f;
  for (int t = 0; t < SEQL; t++) acc += (xb[t * CIN] - mu) * wp[t];
  pre[((size_t)b * TT + p) * CIN + c] = acc * inv + bias[p];
}

__global__ void pl2_kernel(const float* __restrict__ pre, const float* __restrict__ w,
                           const float* __restrict__ bias, float* __restrict__ out) {
  int q = blockIdx.x, b = blockIdx.y, c = threadIdx.x;  // 64 threads
  const float* pb = pre + (size_t)b * TT * CIN + c;
  const float* wq = w + q * TT;
  float acc = 0.f;
  for (int p = 0; p < TT; p++) acc += pb[p * CIN] * wq[p];
  out[((size_t)b * TT + q) * CIN + c] = acc + bias[q];
}

// emb = circular-conv3(corrupt) + pos_emb + mark@tf_w ; also bf16 copy
__global__ void embed_kernel(const float* __restrict__ corrupt, const float* __restrict__ ymark,
                             const float* __restrict__ conv_w, const float* __restrict__ tf_w,
                             float* __restrict__ emb, unsigned short* __restrict__ embB) {
  int t = blockIdx.x, b = blockIdx.y, d = threadIdx.x;  // 512 threads
  __shared__ float xm[CIN], x0[CIN], xp[CIN], mk[4];
  int tm = (t + TT - 1) % TT, tp = (t + 1) % TT;
  if (d < CIN) {
    xm[d] = corrupt[((size_t)b * TT + tm) * CIN + d];
    x0[d] = corrupt[((size_t)b * TT + t) * CIN + d];
    xp[d] = corrupt[((size_t)b * TT + tp) * CIN + d];
  }
  if (d < 4) mk[d] = ymark[((size_t)b * 240 + 48 + t) * 4 + d];
  __syncthreads();
  float acc = 0.f;
  const float* w0 = conv_w + d;
  const float* w1 = conv_w + CIN * DM + d;
  const float* w2 = conv_w + 2 * CIN * DM + d;
  #pragma unroll 8
  for (int c = 0; c < CIN; c++)
    acc += xm[c] * w0[c * DM] + x0[c] * w1[c * DM] + xp[c] * w2[c * DM];
  int i2 = (d >> 1) * 2;
  float freq = expf((float)i2 * (-9.210340371976184f / (float)DM));
  float ang = (float)t * freq;
  float pe = (d & 1) ? cosf(ang) : sinf(ang);
  float mkacc = mk[0] * tf_w[d] + mk[1] * tf_w[DM + d] + mk[2] * tf_w[2 * DM + d] +
                mk[3] * tf_w[3 * DM + d];
  float val = acc + pe + mkacc;
  size_t o = ((size_t)b * TT + t) * DM + d;
  emb[o] = val;
  embB[o] = f2bf(val);
}

// ---------------- fp32 GEMM (kept for proj N=64) ----------------
template <int TB, int RELU>
__global__ __launch_bounds__(256) void gemm_kernel(const float* __restrict__ A,
                                                   const float* __restrict__ B,
                                                   const float* __restrict__ bias,
                                                   float* __restrict__ C, int M, int N, int K) {
  __shared__ float As[16][68];
  __shared__ float Bs[16][68];
  int tid = threadIdx.x;
  int bn = blockIdx.x * 64, bm = blockIdx.y * 64;
  int tx = tid & 15, ty = tid >> 4;
  int row0 = ty * 4, col0 = tx * 4;
  float acc[4][4] = {};
  for (int k0 = 0; k0 < K; k0 += 16) {
    {
      int m = tid >> 2, kq = (tid & 3) << 2;
      float4 av = *(const float4*)&A[(size_t)(bm + m) * K + k0 + kq];
      As[kq + 0][m] = av.x; As[kq + 1][m] = av.y; As[kq + 2][m] = av.z; As[kq + 3][m] = av.w;
    }
    if (TB) {
      int n = tid >> 2, kq = (tid & 3) << 2;
      float4 bv = *(const float4*)&B[(size_t)(bn + n) * K + k0 + kq];
      Bs[kq + 0][n] = bv.x; Bs[kq + 1][n] = bv.y; Bs[kq + 2][n] = bv.z; Bs[kq + 3][n] = bv.w;
    } else {
      int kk = tid >> 4, nq = (tid & 15) << 2;
      float4 bv = *(const float4*)&B[(size_t)(k0 + kk) * N + bn + nq];
      *(float4*)&Bs[kk][nq] = bv;
    }
    __syncthreads();
    #pragma unroll
    for (int k = 0; k < 16; k++) {
      float4 a4 = *(const float4*)&As[k][row0];
      float4 b4 = *(const float4*)&Bs[k][col0];
      float a[4] = {a4.x, a4.y, a4.z, a4.w};
      float bb[4] = {b4.x, b4.y, b4.z, b4.w};
      #pragma unroll
      for (int i = 0; i < 4; i++)
        #pragma unroll
        for (int j = 0; j < 4; j++) acc[i][j] += a[i] * bb[j];
    }
    __syncthreads();
  }
  float bv[4] = {0.f, 0.f, 0.f, 0.f};
  if (bias) *(float4*)bv = *(const float4*)&bias[bn + col0];
  #pragma unroll
  for (int i = 0; i < 4; i++) {
    float ov[4];
    #pragma unroll
    for (int j = 0; j < 4; j++) {
      float v = acc[i][j] + bv[j];
      if (RELU) v = fmaxf(v, 0.f);
      ov[j] = v;
    }
    *(float4*)&C[(size_t)(bm + row0 + i) * N + bn + col0] = *(float4*)ov;
  }
}

// ---------------- bf16 MFMA GEMM (bf16 A, bf16 Bt [N][K]) ----------------
template <int RELU, int WF32, int WBF16, int AXPY>
__global__ __launch_bounds__(256) void gemm_bf16_kernel(
    const unsigned short* __restrict__ A, const unsigned short* __restrict__ Bt,
    const float* __restrict__ bias, float* __restrict__ C, unsigned short* __restrict__ Cb,
    const float* __restrict__ R, const float* __restrict__ alphaPtr, int M, int N, int K) {
  __shared__ __align__(16) unsigned short As[128 * 40];
  __shared__ __align__(16) unsigned short Bs[128 * 40];
  int tid = threadIdx.x;
  int bm = blockIdx.y * 128, bn = blockIdx.x * 128;
  int wave = tid >> 6, lane = tid & 63;
  int wm = (wave >> 1) * 64, wn = (wave & 1) * 64;
  int r15 = lane & 15, q = lane >> 4;
  f32x4 acc[4][4] = {};
  int sr = tid >> 1, sh = (tid & 1) * 16;
  for (int k0 = 0; k0 < K; k0 += 32) {
    {
      const unsigned short* ap = &A[(size_t)(bm + sr) * K + k0 + sh];
      *(uint4*)&As[sr * 40 + sh] = *(const uint4*)ap;
      *(uint4*)&As[sr * 40 + sh + 8] = *(const uint4*)(ap + 8);
    }
    {
      const unsigned short* bp = &Bt[(size_t)(bn + sr) * K + k0 + sh];
      *(uint4*)&Bs[sr * 40 + sh] = *(const uint4*)bp;
      *(uint4*)&Bs[sr * 40 + sh + 8] = *(const uint4*)(bp + 8);
    }
    __syncthreads();
    bf16x8 af[4], bfr[4];
    #pragma unroll
    for (int mi = 0; mi < 4; mi++)
      af[mi] = *(const bf16x8*)&As[(wm + mi * 16 + r15) * 40 + q * 8];
    #pragma unroll
    for (int ni = 0; ni < 4; ni++)
      bfr[ni] = *(const bf16x8*)&Bs[(wn + ni * 16 + r15) * 40 + q * 8];
    #pragma unroll
    for (int mi = 0; mi < 4; mi++)
      #pragma unroll
      for (int ni = 0; ni < 4; ni++)
        acc[mi][ni] =
            __builtin_amdgcn_mfma_f32_16x16x32_bf16(af[mi], bfr[ni], acc[mi][ni], 0, 0, 0);
    __syncthreads();
  }
  float al = AXPY ? alphaPtr[0] : 0.f;
  #pragma unroll
  for (int mi = 0; mi < 4; mi++) {
    #pragma unroll
    for (int ni = 0; ni < 4; ni++) {
      int col = bn + wn + ni * 16 + r15;
      float bv = (bias && !AXPY) ? bias[col] : 0.f;
      #pragma unroll
      for (int v = 0; v < 4; v++) {
        int row = bm + wm + mi * 16 + q * 4 + v;
        float val = acc[mi][ni][v] + bv;
        if (RELU) val = fmaxf(val, 0.f);
        if (WF32) C[(size_t)row * N + col] = val;
        if (WBF16) Cb[(size_t)row * N + col] = f2bf(val);
        if (AXPY) {
          if (col < 64)
            C[(size_t)row * 64 + col] = R[(size_t)row * 64 + col] - al * val;
        }
      }
    }
  }
}

// tiled transpose-pack: dst[n*K + k] = bf16(src[k*N + n]); coalesced both sides
__global__ __launch_bounds__(256) void pack_transpose_bf16_kernel(
    const float* __restrict__ src, unsigned short* __restrict__ dst, int K, int N) {
  __shared__ unsigned short tile[64][65];
  int kb = blockIdx.x * 64, nb = blockIdx.y * 64;
  int tid = threadIdx.x;
  int tn = tid & 63, tk = tid >> 6;  // 4 rows per pass
  #pragma unroll
  for (int i = 0; i < 16; i++) {
    int k = tk + i * 4;
    tile[k][tn] = f2bf(src[(size_t)(kb + k) * N + nb + tn]);
  }
  __syncthreads();
  int tk2 = tid & 63, tn2 = tid >> 6;
  #pragma unroll
  for (int i = 0; i < 16; i++) {
    int n = tn2 + i * 4;
    dst[(size_t)(nb + n) * K + kb + tk2] = tile[tk2][n];
  }
}

__global__ void pack_bf16_kernel(const float* __restrict__ src, unsigned short* __restrict__ dst,
                                 int n) {
  int idx = blockIdx.x * 256 + threadIdx.x;
  if (idx < n) dst[idx] = f2bf(src[idx]);
}

// WxProjB[n][k] (n<128, k<1536) = n<64 ? bf16(wih[k*128 + n]) : 0
__global__ void pack_wxproj_kernel(const float* __restrict__ wih,
                                   unsigned short* __restrict__ dst) {
  int idx = blockIdx.x * 256 + threadIdx.x;  // 128*1536
  int k = idx % 1536, n = idx / 1536;
  float v = (n < 64) ? wih[(size_t)k * 128 + n] : 0.f;
  dst[idx] = f2bf(v);
}

__global__ void concat_qkv_bias_kernel(const float* __restrict__ bq, const float* __restrict__ bk,
                                       const float* __restrict__ bv, float* __restrict__ dst) {
  int l = blockIdx.y;
  int i = blockIdx.x * 256 + threadIdx.x;  // < 1536
  float v = (i < 512) ? bq[l * 512 + i]
                      : ((i < 1024) ? bk[l * 512 + i - 512] : bv[l * 512 + i - 1024]);
  dst[l * 1536 + i] = v;
}

// ---------------- MFMA attention: one block per (h,b) ----------------
__global__ __launch_bounds__(256) void attention_mfma_kernel(
    const unsigned short* __restrict__ qkv, unsigned short* __restrict__ attnO) {
  __shared__ __align__(16) unsigned short Ks[192 * 72];
  __shared__ __align__(16) unsigned short Vt[64 * 200];
  __shared__ __align__(16) float Ps[4][16 * 36];
  int h = blockIdx.x, b = blockIdx.y;
  int tid = threadIdx.x, wave = tid >> 6, lane = tid & 63;
  int m = lane & 15, q = lane >> 4;
  const unsigned short* Qg = qkv + (size_t)b * TT * 1536 + h * 64;
  const unsigned short* Kg = Qg + 512;
  const unsigned short* Vg = Qg + 1024;
  for (int idx = tid; idx < 192 * 8; idx += 256) {
    int s = idx >> 3, ch = (idx & 7) * 8;
    *(uint4*)&Ks[s * 72 + ch] = *(const uint4*)&Kg[(size_t)s * 1536 + ch];
  }
  for (int idx = tid; idx < 96 * 8; idx += 256) {
    int sp = idx >> 3, co = (idx & 7) * 8;
    uint4 v0 = *(const uint4*)&Vg[(size_t)(2 * sp) * 1536 + co];
    uint4 v1 = *(const uint4*)&Vg[(size_t)(2 * sp + 1) * 1536 + co];
    const unsigned short* e0 = (const unsigned short*)&v0;
    const unsigned short* e1 = (const unsigned short*)&v1;
    unsigned int* vtw = (unsigned int*)Vt;
    #pragma unroll
    for (int u = 0; u < 8; u++)
      vtw[(co + u) * 100 + sp] = (unsigned int)e0[u] | ((unsigned int)e1[u] << 16);
  }
  __syncthreads();
  float* ps = Ps[wave];
  for (int tile = wave; tile < 12; tile += 4) {
    int t0 = tile * 16;
    bf16x8 qf0 = *(const bf16x8*)&Qg[(size_t)(t0 + m) * 1536 + q * 8];
    bf16x8 qf1 = *(const bf16x8*)&Qg[(size_t)(t0 + m) * 1536 + 32 + q * 8];
    f32x4 S[12];
    #pragma unroll
    for (int nt = 0; nt < 12; nt++) {
      bf16x8 kf0 = *(const bf16x8*)&Ks[(nt * 16 + m) * 72 + q * 8];
      bf16x8 kf1 = *(const bf16x8*)&Ks[(nt * 16 + m) * 72 + 32 + q * 8];
      f32x4 a = {0.f, 0.f, 0.f, 0.f};
      a = __builtin_amdgcn_mfma_f32_16x16x32_bf16(qf0, kf0, a, 0, 0, 0);
      a = __builtin_amdgcn_mfma_f32_16x16x32_bf16(qf1, kf1, a, 0, 0, 0);
      S[nt] = a;
    }
    float mx[4] = {-1e30f, -1e30f, -1e30f, -1e30f};
    #pragma unroll
    for (int nt = 0; nt < 12; nt++)
      #pragma unroll
      for (int v = 0; v < 4; v++) {
        S[nt][v] *= 0.125f;
        mx[v] = fmaxf(mx[v], S[nt][v]);
      }
    #pragma unroll
    for (int d = 1; d < 16; d <<= 1) {
      #pragma unroll
      for (int v = 0; v < 4; v++) mx[v] = fmaxf(mx[v], __shfl_xor(mx[v], d));
    }
    float sm[4] = {0.f, 0.f, 0.f, 0.f};
    #pragma unroll
    for (int nt = 0; nt < 12; nt++)
      #pragma unroll
      for (int v = 0; v < 4; v++) {
        float e = __expf(S[nt][v] - mx[v]);
        S[nt][v] = e;
        sm[v] += e;
      }
    #pragma unroll
    for (int d = 1; d < 16; d <<= 1) {
      #pragma unroll
      for (int v = 0; v < 4; v++) sm[v] += __shfl_xor(sm[v], d);
    }
    float inv[4];
    #pragma unroll
    for (int v = 0; v < 4; v++) inv[v] = 1.f / sm[v];
    f32x4 o[4] = {};
    for (int kc = 0; kc < 6; kc++) {
      asm volatile("s_waitcnt lgkmcnt(0)" ::: "memory");
      #pragma unroll
      for (int half = 0; half < 2; half++) {
        int nt = 2 * kc + half;
        #pragma unroll
        for (int v = 0; v < 4; v++) ps[(q * 4 + v) * 36 + half * 16 + m] = S[nt][v];
      }
      asm volatile("s_waitcnt lgkmcnt(0)" ::: "memory");
      float4 p0 = *(const float4*)&ps[m * 36 + q * 8];
      float4 p1 = *(const float4*)&ps[m * 36 + q * 8 + 4];
      unsigned short tmp[8];
      tmp[0] = f2bf(p0.x); tmp[1] = f2bf(p0.y); tmp[2] = f2bf(p0.z); tmp[3] = f2bf(p0.w);
      tmp[4] = f2bf(p1.x); tmp[5] = f2bf(p1.y); tmp[6] = f2bf(p1.z); tmp[7] = f2bf(p1.w);
      bf16x8 pf = *(bf16x8*)tmp;
      #pragma unroll
      for (int nt2 = 0; nt2 < 4; nt2++) {
        bf16x8 vf = *(const bf16x8*)&Vt[(nt2 * 16 + m) * 200 + kc * 32 + q * 8];
        o[nt2] = __builtin_amdgcn_mfma_f32_16x16x32_bf16(pf, vf, o[nt2], 0, 0, 0);
      }
    }
    #pragma unroll
    for (int nt2 = 0; nt2 < 4; nt2++)
      #pragma unroll
      for (int v = 0; v < 4; v++) {
        size_t row = (size_t)b * TT + t0 + q * 4 + v;
        attnO[row * 512 + h * 64 + nt2 * 16 + m] = f2bf(o[nt2][v] * inv[v]);
      }
  }
}

// ---------------- layernorm with residual, in-place on x; bf16 copy ----------------
__global__ __launch_bounds__(256) void ln_residual_kernel(float* __restrict__ x,
                                                          const float* __restrict__ res,
                                                          const float* __restrict__ g,
                                                          const float* __restrict__ b,
                                                          unsigned short* __restrict__ xb) {
  int row = blockIdx.x, tid = threadIdx.x;
  __shared__ float red[256];
  float* xr = x + (size_t)row * DM;
  const float* rr = res + (size_t)row * DM;
  float v0 = xr[tid] + rr[tid];
  float v1 = xr[tid + 256] + rr[tid + 256];
  red[tid] = v0 + v1;
  __syncthreads();
  for (int s = 128; s > 0; s >>= 1) {
    if (tid < s) red[tid] += red[tid + s];
    __syncthreads();
  }
  float mu = red[0] * (1.f / DM);
  __syncthreads();
  float d0 = v0 - mu, d1 = v1 - mu;
  red[tid] = d0 * d0 + d1 * d1;
  __syncthreads();
  for (int s = 128; s > 0; s >>= 1) {
    if (tid < s) red[tid] += red[tid + s];
    __syncthreads();
  }
  float rstd = rsqrtf(red[0] * (1.f / DM) + 1e-5f);
  float o0 = d0 * rstd * g[tid] + b[tid];
  float o1 = d1 * rstd * g[tid + 256] + b[tid + 256];
  xr[tid] = o0;
  xr[tid + 256] = o1;
  xb[(size_t)row * DM + tid] = f2bf(o0);
  xb[(size_t)row * DM + tid + 256] = f2bf(o1);
}

__global__ void xcat_kernel(const float* __restrict__ corrupt, const float* __restrict__ cond,
                            unsigned short* __restrict__ xcatB) {
  int r = blockIdx.x, tid = threadIdx.x;  // 128 threads
  float v = (tid < 64) ? corrupt[(size_t)r * 64 + tid] : cond[(size_t)r * 64 + (tid - 64)];
  xcatB[(size_t)r * 128 + tid] = f2bf(v);
}

// ---------------- whh i8 pack, j-split (quad) layout ----------------
// whhJ entry: ((((quad*8+kh)*4+u)*3+g)*128 + jl)*16 + m ; k = kh*64+u*16+m, j = quad*128+jl
__global__ void pack_whh_q8_kernel(const float* __restrict__ whh, signed char* __restrict__ whhJ,
                                   float* __restrict__ sws) {
  int row = blockIdx.x;   // 0..1535 = g*512 + j
  int lane = threadIdx.x; // 64
  const float* src = whh + (size_t)row * 512;
  float mx = 0.f;
  for (int k = lane; k < 512; k += 64) mx = fmaxf(mx, fabsf(src[k]));
  for (int off = 32; off > 0; off >>= 1) mx = fmaxf(mx, __shfl_xor(mx, off));
  float inv = (mx > 0.f) ? 127.f / mx : 0.f;
  if (lane == 0) sws[row] = (mx / 127.f) * (8.f / 127.f);
  int g = row >> 9, j = row & 511;
  int quad = j >> 7, jl = j & 127;
  for (int k = lane; k < 512; k += 64) {
    int qv = (int)rintf(src[k] * inv);
    qv = qv < -127 ? -127 : (qv > 127 ? 127 : qv);
    int kh = k >> 6, u = (k >> 4) & 3, m = k & 15;
    whhJ[((size_t)((((quad * 8 + kh) * 4 + u) * 3 + g) * 128 + jl)) * 16 + m] = (signed char)qv;
  }
}

// ---------------- Langevin scan: 4 blocks per batch (j-split), i8 sdot4 ----------------
// grid (BATCH, 4), 1024 thr. Exchanges i8 h-quarters via agent-scope atomics.
__global__ __launch_bounds__(1024) void langevin_scan_kernel(
    const float* __restrict__ gi_all, const float* __restrict__ hx0,
    const signed char* __restrict__ whhJ, const float* __restrict__ sws,
    const float* __restrict__ bhh, const float* __restrict__ score_w,
    unsigned short* __restrict__ dgiB, unsigned int* __restrict__ hqg,
    unsigned int* __restrict__ flags) {
  int b = blockIdx.x, quad = blockIdx.y;
  int tid = threadIdx.x;
  __shared__ float hloc[128];
  __shared__ __align__(16) unsigned int hq8[128];
  __shared__ int prI[1024], pzI[1024], pnI[1024];
  int jl = tid & 127, kh = tid >> 7;
  int j = quad * 128 + jl;
  float bhr = 0.f, bhz = 0.f, bhn = 0.f, sw = 0.f, swr = 0.f, swz = 0.f, swn = 0.f;
  if (tid < 128) {
    bhr = bhh[j]; bhz = bhh[512 + j]; bhn = bhh[1024 + j];
    sw = score_w[j] * COF;
    swr = sws[j]; swz = sws[512 + j]; swn = sws[1024 + j];
    hloc[tid] = hx0[(size_t)b * 512 + j];
    float4 hv = *(const float4*)&hx0[(size_t)b * 512 + tid * 4];
    float tmp[4] = {hv.x, hv.y, hv.z, hv.w};
    hq8[tid] = packq4(tmp);
  }
  __syncthreads();
  const uint4* wq = (const uint4*)whhJ + (size_t)quad * (8 * 4 * 3 * 128);
  const uint4* wk = wq + (size_t)kh * (4 * 3 * 128) + jl;
  for (int t = 0; t < TT; t++) {
    int ir = 0, iz = 0, in_ = 0;
    #pragma unroll
    for (int u = 0; u < 4; u++) {
      uint4 hqv = *(const uint4*)&hq8[kh * 16 + u * 4];
      uint4 wr = wk[(u * 3 + 0) * 128];
      uint4 wz = wk[(u * 3 + 1) * 128];
      uint4 wn = wk[(u * 3 + 2) * 128];
      ir = sd4(wr.x, hqv.x, ir); ir = sd4(wr.y, hqv.y, ir);
      ir = sd4(wr.z, hqv.z, ir); ir = sd4(wr.w, hqv.w, ir);
      iz = sd4(wz.x, hqv.x, iz); iz = sd4(wz.y, hqv.y, iz);
      iz = sd4(wz.z, hqv.z, iz); iz = sd4(wz.w, hqv.w, iz);
      in_ = sd4(wn.x, hqv.x, in_); in_ = sd4(wn.y, hqv.y, in_);
      in_ = sd4(wn.z, hqv.z, in_); in_ = sd4(wn.w, hqv.w, in_);
    }
    prI[tid] = ir; pzI[tid] = iz; pnI[tid] = in_;
    __syncthreads();
    if (tid < 128) {
      int sr_ = 0, sz_ = 0, sn_ = 0;
      #pragma unroll
      for (int kk = 0; kk < 8; kk++) {
        sr_ += prI[kk * 128 + jl];
        sz_ += pzI[kk * 128 + jl];
        sn_ += pnI[kk * 128 + jl];
      }
      float gr = (float)sr_ * swr, gz = (float)sz_ * swz, gn = (float)sn_ * swn;
      const float* gi = &gi_all[((size_t)b * TT + t) * 1536];
      float gir = gi[j], giz = gi[512 + j], gin = gi[1024 + j];
      float r = 1.f / (1.f + expf(-(gir + gr + bhr)));
      float z = 1.f / (1.f + expf(-(giz + gz + bhz)));
      float hnv = gn + bhn;
      float hj = hloc[jl];
      float n = tanhf(gin + r * hnv);
      float dinn = sw * (1.f - z) * (1.f - n * n);
      size_t drow = ((size_t)b * TT + t) * 1536;
      dgiB[drow + j] = f2bf(dinn * hnv * r * (1.f - r));
      dgiB[drow + 512 + j] = f2bf(sw * (hj - n) * z * (1.f - z));
      dgiB[drow + 1024 + j] = f2bf(dinn);
      hloc[jl] = (1.f - z) * n + z * hj;
    }
    __syncthreads();
    if (t + 1 < TT) {
      int slot = t & 1;
      if (tid < 32) {
        float tmp[4] = {hloc[tid * 4], hloc[tid * 4 + 1], hloc[tid * 4 + 2], hloc[tid * 4 + 3]};
        unsigned int v = packq4(tmp);
        hq8[quad * 32 + tid] = v;
        __hip_atomic_store(&hqg[(((size_t)slot * BATCH + b) * 4 + quad) * 32 + tid], v,
                           __ATOMIC_RELAXED, __HIP_MEMORY_SCOPE_AGENT);
      }
      if (tid == 0)
        __hip_atomic_store(&flags[b * 4 + quad], (unsigned)(t + 1), __ATOMIC_RELEASE,
                           __HIP_MEMORY_SCOPE_AGENT);
      if (tid < 3) {
        int oq = (quad + 1 + tid) & 3;
        while (__hip_atomic_load(&flags[b * 4 + oq], __ATOMIC_ACQUIRE,
                                 __HIP_MEMORY_SCOPE_AGENT) < (unsigned)(t + 1)) {
          __builtin_amdgcn_s_sleep(4);
        }
      }
      __syncthreads();
      if (tid < 96) {
        int o = tid >> 5, w = tid & 31;
        int oq = (quad + 1 + o) & 3;
        hq8[oq * 32 + w] =
            __hip_atomic_load(&hqg[(((size_t)slot * BATCH + b) * 4 + oq) * 32 + w],
                              __ATOMIC_RELAXED, __HIP_MEMORY_SCOPE_AGENT);
      }
      __syncthreads();
    }
  }
}

// denorm + write d_out + loss partial
__global__ __launch_bounds__(256) void denorm_loss_kernel(
    const float* __restrict__ outb, const float* __restrict__ stdev,
    const float* __restrict__ means, const float* __restrict__ y, float* __restrict__ dout,
    float* __restrict__ loss) {
  int idx = blockIdx.x * 256 + threadIdx.x;
  int tid = threadIdx.x;
  int c = idx & 63;
  int bt = idx >> 6;
  int t = bt % TT, b = bt / TT;
  float od = outb[idx] * stdev[b * CIN + c] + means[b * CIN + c];
  dout[idx] = od;
  float diff = fabsf(od - y[((size_t)b * 240 + 48 + t) * CIN + c]);
  __shared__ float red[256];
  red[tid] = diff;
  __syncthreads();
  for (int s = 128; s > 0; s >>= 1) {
    if (tid < s) red[tid] += red[tid + s];
    __syncthreads();
  }
  if (tid == 0) atomicAdd(loss, red[0]);
}

// ---------------- host launch ----------------
extern "C" void kernel_launch(void* const* d_in, const int* in_sizes, int n_in, void* d_out,
                              int out_size, void* d_ws, size_t ws_size, hipStream_t stream) {
  const float* x_enc = (const float*)d_in[0];
  const float* batch_y = (const float*)d_in[2];
  const float* y_mark = (const float*)d_in[3];
  const float* hx_init = (const float*)d_in[4];
  const float* conv_w = (const float*)d_in[5];
  const float* tf_w = (const float*)d_in[6];
  const float* Wq = (const float*)d_in[7];
  const float* Wk = (const float*)d_in[8];
  const float* Wv = (const float*)d_in[9];
  const float* Wo = (const float*)d_in[10];
  const float* bq = (const float*)d_in[11];
  const float* bk = (const float*)d_in[12];
  const float* bv = (const float*)d_in[13];
  const float* bo = (const float*)d_in[14];
  const float* ln1_g = (const float*)d_in[15];
  const float* ln1_b = (const float*)d_in[16];
  const float* W1 = (const float*)d_in[17];
  const float* b1 = (const float*)d_in[18];
  const float* W2 = (const float*)d_in[19];
  const float* b2 = (const float*)d_in[20];
  const float* ln2_g = (const float*)d_in[21];
  const float* ln2_b = (const float*)d_in[22];
  const float* pl1_w = (const float*)d_in[23];
  const float* pl1_b = (const float*)d_in[24];
  const float* pl2_w = (const float*)d_in[25];
  const float* pl2_b = (const float*)d_in[26];
  const float* proj_w = (const float*)d_in[27];
  const float* proj_b = (const float*)d_in[28];
  const float* gru_wih = (const float*)d_in[29];
  const float* gru_whh = (const float*)d_in[30];
  const float* gru_bih = (const float*)d_in[31];
  const float* gru_bhh = (const float*)d_in[32];
  const float* score_w = (const float*)d_in[33];
  const float* alpha = (const float*)d_in[34];
  float* dout = (float*)d_out;

  float* W = (float*)d_ws;
  size_t off = 0;
  float* means = W + off;   off += 2048;
  float* stdev = W + off;   off += 2048;
  float* lossacc = W + off; off += 64;
  float* preA = W + off;    off += (size_t)OUTN;
  float* outA = W + off;    off += (size_t)OUTN;
  float* outB = W + off;    off += (size_t)OUTN;
  float* corrupt = W + off; off += (size_t)OUTN;
  float* cond = W + off;    off += (size_t)OUTN;
  signed char* whhJ = (signed char*)(W + off); off += 786432 / 4;
  float* sws = W + off;     off += 1536;
  unsigned int* flagsU = (unsigned int*)(W + off); off += 128;
  unsigned int* hqg = (unsigned int*)(W + off);    off += 2 * BATCH * 4 * 32;
  float* emb = W + off;     off += (size_t)BATCH * TT * DM;
  float* Kb = W + off;      off += (size_t)BATCH * TT * DM;
  float* gi_all = W + off;  off += (size_t)BATCH * TT * 1536;
  unsigned short* embB = (unsigned short*)(W + off);  off += (size_t)BATCH * TT * DM / 2;
  unsigned short* qkvB = (unsigned short*)(W + off);  off += (size_t)BATCH * TT * 1536 / 2;
  unsigned short* attnOB = (unsigned short*)(W + off); off += (size_t)BATCH * TT * DM / 2;
  unsigned short* FFbB = (unsigned short*)(W + off);  off += (size_t)BATCH * TT * DFF / 2;
  unsigned short* xcatB = (unsigned short*)(W + off); off += (size_t)BATCH * TT * 128 / 2;
  float* bqkv = W + off;    off += 2 * 1536;
  unsigned short* WxProjB = (unsigned short*)(W + off); off += (size_t)128 * 1536 / 2;
  unsigned short* wT = (unsigned short*)(W + off);
  const size_t SQ = (size_t)DM * DM;
  const size_t SFF = (size_t)DM * DFF;
  const size_t LAYER = 4 * SQ + 2 * SFF;
  unsigned short* wihB = wT + 2 * LAYER;
  off += (2 * LAYER + (size_t)1536 * 128) / 2 + 64;
  unsigned short* dgiB = qkvB;  // alias: qkvB dead after attention, reused for dgi

  const int M = BATCH * TT;  // 6144

  zero_loss_kernel<<<1, 64, 0, stream>>>(lossacc);
  stats_kernel<<<BATCH, 64, 0, stream>>>(x_enc, means, stdev);
  pl1_kernel<<<dim3(TT, BATCH), 64, 0, stream>>>(x_enc, means, stdev, pl1_w, pl1_b, preA);
  pack_whh_q8_kernel<<<1536, 64, 0, stream>>>(gru_whh, whhJ, sws);
  pack_wxproj_kernel<<<(128 * 1536) / 256, 256, 0, stream>>>(gru_wih, WxProjB);
  concat_qkv_bias_kernel<<<dim3(6, 2), 256, 0, stream>>>(bq, bk, bv, bqkv);
  for (int l = 0; l < 2; l++) {
    unsigned short* base = wT + (size_t)l * LAYER;
    pack_transpose_bf16_kernel<<<dim3(8, 8), 256, 0, stream>>>(Wq + (size_t)l * SQ, base, DM, DM);
    pack_transpose_bf16_kernel<<<dim3(8, 8), 256, 0, stream>>>(Wk + (size_t)l * SQ, base + SQ, DM, DM);
    pack_transpose_bf16_kernel<<<dim3(8, 8), 256, 0, stream>>>(Wv + (size_t)l * SQ, base + 2 * SQ, DM, DM);
    pack_transpose_bf16_kernel<<<dim3(8, 8), 256, 0, stream>>>(Wo + (size_t)l * SQ, base + 3 * SQ, DM, DM);
    pack_transpose_bf16_kernel<<<dim3(8, 32), 256, 0, stream>>>(W1 + (size_t)l * SFF, base + 4 * SQ, DM, DFF);
    pack_transpose_bf16_kernel<<<dim3(32, 8), 256, 0, stream>>>(W2 + (size_t)l * SFF, base + 4 * SQ + SFF, DFF, DM);
  }
  pack_bf16_kernel<<<(1536 * 128) / 256, 256, 0, stream>>>(gru_wih, wihB, 1536 * 128);

  const float* pre = preA;
  float* outs[2] = {outA, outB};
  for (int s = 0; s < 2; s++) {
    pl2_kernel<<<dim3(TT, BATCH), 64, 0, stream>>>(pre, pl2_w, pl2_b, corrupt);
    embed_kernel<<<dim3(TT, BATCH), DM, 0, stream>>>(corrupt, y_mark, conv_w, tf_w, emb, embB);
    for (int l = 0; l < 2; l++) {
      unsigned short* base = wT + (size_t)l * LAYER;
      gemm_bf16_kernel<0, 0, 1, 0><<<dim3(1536 / 128, M / 128), 256, 0, stream>>>(
          embB, base, bqkv + l * 1536, nullptr, qkvB, nullptr, nullptr, M, 1536, DM);
      attention_mfma_kernel<<<dim3(NH, BATCH), 256, 0, stream>>>(qkvB, attnOB);
      gemm_bf16_kernel<0, 1, 0, 0><<<dim3(DM / 128, M / 128), 256, 0, stream>>>(
          attnOB, base + 3 * SQ, bo + l * DM, Kb, nullptr, nullptr, nullptr, M, DM, DM);
      ln_residual_kernel<<<M, 256, 0, stream>>>(emb, Kb, ln1_g + l * DM, ln1_b + l * DM, embB);
      gemm_bf16_kernel<1, 0, 1, 0><<<dim3(DFF / 128, M / 128), 256, 0, stream>>>(
          embB, base + 4 * SQ, b1 + l * DFF, nullptr, FFbB, nullptr, nullptr, M, DFF, DM);
      gemm_bf16_kernel<0, 1, 0, 0><<<dim3(DM / 128, M / 128), 256, 0, stream>>>(
          FFbB, base + 4 * SQ + SFF, b2 + l * DM, Kb, nullptr, nullptr, nullptr, M, DM, DFF);
      ln_residual_kernel<<<M, 256, 0, stream>>>(emb, Kb, ln2_g + l * DM, ln2_b + l * DM, embB);
    }
    gemm_kernel<1, 0><<<dim3(CIN / 64, M / 64), 256, 0, stream>>>(
        emb, proj_w, proj_b, cond, M, CIN, DM);
    xcat_kernel<<<M, 128, 0, stream>>>(corrupt, cond, xcatB);
    gemm_bf16_kernel<0, 1, 0, 0><<<dim3(1536 / 128, M / 128), 256, 0, stream>>>(
        xcatB, wihB, gru_bih, gi_all, nullptr, nullptr, nullptr, M, 1536, 128);
    zero_flags_kernel<<<1, 128, 0, stream>>>(flagsU);
    langevin_scan_kernel<<<dim3(BATCH, 4), 1024, 0, stream>>>(
        gi_all, hx_init + (size_t)s * BATCH * DM, whhJ, sws, gru_bhh, score_w, dgiB, hqg,
        flagsU);
    // out = xi - alpha * dgi @ Wx^T   (AXPY epilogue)
    gemm_bf16_kernel<0, 0, 0, 1><<<dim3(1, M / 128), 256, 0, stream>>>(
        dgiB, WxProjB, nullptr, outs[s], nullptr, corrupt, alpha, M, 128, 1536);
    denorm_loss_kernel<<<OUTN / 256, 256, 0, stream>>>(outs[s], stdev, means, batch_y, dout,
                                                       lossacc);
    pre = outs[s];
  }
  finalize_kernel<<<1, 1, 0, stream>>>(dout, lossacc);
}

// Round 10
// 2693.770 us; speedup vs baseline: 3.0290x; 1.0067x over previous
//
#include <hip/hip_runtime.h>
#include <math.h>

#define BATCH 32
#define TT    192
#define DM    512
#define CIN   64
#define SEQL  336
#define DFF   2048
#define NH    8
#define COF   0.1f
#define OUTN  (BATCH*TT*CIN)   // 393216

typedef _Float16 h2_t __attribute__((ext_vector_type(2)));
union H2U { unsigned int u; h2_t h; };

typedef short bf16x8 __attribute__((ext_vector_type(8)));
typedef float f32x4 __attribute__((ext_vector_type(4)));

__device__ __forceinline__ unsigned short f2bf(float v) {
  union { float f; unsigned int u; } a; a.f = v;
  unsigned int r = (a.u + 0x7fffu + ((a.u >> 16) & 1u)) >> 16;  // RNE
  return (unsigned short)r;
}

// signed 4x i8 dot product with i32 accumulate
__device__ __forceinline__ int sd4(unsigned int a, unsigned int b, int c) {
#if __has_builtin(__builtin_amdgcn_sdot4)
  return __builtin_amdgcn_sdot4((int)a, (int)b, c, false);
#else
  c += (int)(signed char)(a & 0xff) * (int)(signed char)(b & 0xff);
  c += (int)(signed char)((a >> 8) & 0xff) * (int)(signed char)((b >> 8) & 0xff);
  c += (int)(signed char)((a >> 16) & 0xff) * (int)(signed char)((b >> 16) & 0xff);
  c += (int)(signed char)(a >> 24) * (int)(signed char)(b >> 24);
  return c;
#endif
}

__device__ __forceinline__ int sd16(uint4 w, uint4 h, int acc) {
  acc = sd4(w.x, h.x, acc); acc = sd4(w.y, h.y, acc);
  acc = sd4(w.z, h.z, acc); acc = sd4(w.w, h.w, acc);
  return acc;
}

// quantize 4 floats (scale 127/8) into one packed i8x4 word
__device__ __forceinline__ unsigned int packq4(const float* hp) {
  int a = (int)rintf(hp[0] * 15.875f); a = a < -127 ? -127 : (a > 127 ? 127 : a);
  int b = (int)rintf(hp[1] * 15.875f); b = b < -127 ? -127 : (b > 127 ? 127 : b);
  int c = (int)rintf(hp[2] * 15.875f); c = c < -127 ? -127 : (c > 127 ? 127 : c);
  int d = (int)rintf(hp[3] * 15.875f); d = d < -127 ? -127 : (d > 127 ? 127 : d);
  return (unsigned int)((a & 0xff) | ((b & 0xff) << 8) | ((c & 0xff) << 16) |
                        ((d & 0xff) << 24));
}

// ---------------- small utility kernels ----------------

__global__ void zero_loss_kernel(float* loss) {
  if (threadIdx.x == 0) loss[0] = 0.f;
}

__global__ void zero_flags_kernel(unsigned int* f) { f[threadIdx.x] = 0u; }  // 128 thr

__global__ void finalize_kernel(float* dout, const float* loss) {
  dout[OUTN] = loss[0] * (1.f / (float)OUTN);
}

__global__ void stats_kernel(const float* __restrict__ x, float* __restrict__ means,
                             float* __restrict__ stdev) {
  int b = blockIdx.x, c = threadIdx.x;  // 64 threads
  const float* xb = x + (size_t)b * SEQL * CIN + c;
  float s = 0.f;
  for (int t = 0; t < SEQL; t++) s += xb[t * CIN];
  float mu = s * (1.f / SEQL);
  float s2 = 0.f;
  for (int t = 0; t < SEQL; t++) { float d = xb[t * CIN] - mu; s2 += d * d; }
  means[b * CIN + c] = mu;
  stdev[b * CIN + c] = sqrtf(s2 * (1.f / SEQL) + 1e-5f);
}

__global__ void pl1_kernel(const float* __restrict__ x, const float* __restrict__ means,
                           const float* __restrict__ stdev, const float* __restrict__ w,
                           const float* __restrict__ bias, float* __restrict__ pre) {
  int p = blockIdx.x, b = blockIdx.y, c = threadIdx.x;  // 64 threads
  float mu = means[b * CIN + c];
  float inv = 1.f / stdev[b * CIN + c];
  const float* xb = x + (size_t)b * SEQL * CIN + c;
  const float* wp = w + p * SEQL;
  float acc = 0.f;
  for (int t = 0; t < SEQL; t++) acc += (xb[t * CIN] - mu) * wp[t];
  pre[((size_t)b * TT + p) * CIN + c] = acc * inv + bias[p];
}

__global__ void pl2_kernel(const float* __restrict__ pre, const float* __restrict__ w,
                           const float* __restrict__ bias, float* __restrict__ out) {
  int q = blockIdx.x, b = blockIdx.y, c = threadIdx.x;  // 64 threads
  const float* pb = pre + (size_t)b * TT * CIN + c;
  const float* wq = w + q * TT;
  float acc = 0.f;
  for (int p = 0; p < TT; p++) acc += pb[p * CIN] * wq[p];
  out[((size_t)b * TT + q) * CIN + c] = acc + bias[q];
}

// emb = circular-conv3(corrupt) + pos_emb + mark@tf_w ; also bf16 copy
__global__ void embed_kernel(const float* __restrict__ corrupt, const float* __restrict__ ymark,
                             const float* __restrict__ conv_w, const float* __restrict__ tf_w,
                             float* __restrict__ emb, unsigned short* __restrict__ embB) {
  int t = blockIdx.x, b = blockIdx.y, d = threadIdx.x;  // 512 threads
  __shared__ float xm[CIN], x0[CIN], xp[CIN], mk[4];
  int tm = (t + TT - 1) % TT, tp = (t + 1) % TT;
  if (d < CIN) {
    xm[d] = corrupt[((size_t)b * TT + tm) * CIN + d];
    x0[d] = corrupt[((size_t)b * TT + t) * CIN + d];
    xp[d] = corrupt[((size_t)b * TT + tp) * CIN + d];
  }
  if (d < 4) mk[d] = ymark[((size_t)b * 240 + 48 + t) * 4 + d];
  __syncthreads();
  float acc = 0.f;
  const float* w0 = conv_w + d;
  const float* w1 = conv_w + CIN * DM + d;
  const float* w2 = conv_w + 2 * CIN * DM + d;
  #pragma unroll 8
  for (int c = 0; c < CIN; c++)
    acc += xm[c] * w0[c * DM] + x0[c] * w1[c * DM] + xp[c] * w2[c * DM];
  int i2 = (d >> 1) * 2;
  float freq = expf((float)i2 * (-9.210340371976184f / (float)DM));
  float ang = (float)t * freq;
  float pe = (d & 1) ? cosf(ang) : sinf(ang);
  float mkacc = mk[0] * tf_w[d] + mk[1] * tf_w[DM + d] + mk[2] * tf_w[2 * DM + d] +
                mk[3] * tf_w[3 * DM + d];
  float val = acc + pe + mkacc;
  size_t o = ((size_t)b * TT + t) * DM + d;
  emb[o] = val;
  embB[o] = f2bf(val);
}

// ---------------- fp32 GEMM (kept for proj N=64) ----------------
template <int TB, int RELU>
__global__ __launch_bounds__(256) void gemm_kernel(const float* __restrict__ A,
                                                   const float* __restrict__ B,
                                                   const float* __restrict__ bias,
                                                   float* __restrict__ C, int M, int N, int K) {
  __shared__ float As[16][68];
  __shared__ float Bs[16][68];
  int tid = threadIdx.x;
  int bn = blockIdx.x * 64, bm = blockIdx.y * 64;
  int tx = tid & 15, ty = tid >> 4;
  int row0 = ty * 4, col0 = tx * 4;
  float acc[4][4] = {};
  for (int k0 = 0; k0 < K; k0 += 16) {
    {
      int m = tid >> 2, kq = (tid & 3) << 2;
      float4 av = *(const float4*)&A[(size_t)(bm + m) * K + k0 + kq];
      As[kq + 0][m] = av.x; As[kq + 1][m] = av.y; As[kq + 2][m] = av.z; As[kq + 3][m] = av.w;
    }
    if (TB) {
      int n = tid >> 2, kq = (tid & 3) << 2;
      float4 bv = *(const float4*)&B[(size_t)(bn + n) * K + k0 + kq];
      Bs[kq + 0][n] = bv.x; Bs[kq + 1][n] = bv.y; Bs[kq + 2][n] = bv.z; Bs[kq + 3][n] = bv.w;
    } else {
      int kk = tid >> 4, nq = (tid & 15) << 2;
      float4 bv = *(const float4*)&B[(size_t)(k0 + kk) * N + bn + nq];
      *(float4*)&Bs[kk][nq] = bv;
    }
    __syncthreads();
    #pragma unroll
    for (int k = 0; k < 16; k++) {
      float4 a4 = *(const float4*)&As[k][row0];
      float4 b4 = *(const float4*)&Bs[k][col0];
      float a[4] = {a4.x, a4.y, a4.z, a4.w};
      float bb[4] = {b4.x, b4.y, b4.z, b4.w};
      #pragma unroll
      for (int i = 0; i < 4; i++)
        #pragma unroll
        for (int j = 0; j < 4; j++) acc[i][j] += a[i] * bb[j];
    }
    __syncthreads();
  }
  float bv[4] = {0.f, 0.f, 0.f, 0.f};
  if (bias) *(float4*)bv = *(const float4*)&bias[bn + col0];
  #pragma unroll
  for (int i = 0; i < 4; i++) {
    float ov[4];
    #pragma unroll
    for (int j = 0; j < 4; j++) {
      float v = acc[i][j] + bv[j];
      if (RELU) v = fmaxf(v, 0.f);
      ov[j] = v;
    }
    *(float4*)&C[(size_t)(bm + row0 + i) * N + bn + col0] = *(float4*)ov;
  }
}

// ---------------- bf16 MFMA GEMM (bf16 A, bf16 Bt [N][K]) ----------------
template <int RELU, int WF32, int WBF16, int AXPY>
__global__ __launch_bounds__(256) void gemm_bf16_kernel(
    const unsigned short* __restrict__ A, const unsigned short* __restrict__ Bt,
    const float* __restrict__ bias, float* __restrict__ C, unsigned short* __restrict__ Cb,
    const float* __restrict__ R, const float* __restrict__ alphaPtr, int M, int N, int K) {
  __shared__ __align__(16) unsigned short As[128 * 40];
  __shared__ __align__(16) unsigned short Bs[128 * 40];
  int tid = threadIdx.x;
  int bm = blockIdx.y * 128, bn = blockIdx.x * 128;
  int wave = tid >> 6, lane = tid & 63;
  int wm = (wave >> 1) * 64, wn = (wave & 1) * 64;
  int r15 = lane & 15, q = lane >> 4;
  f32x4 acc[4][4] = {};
  int sr = tid >> 1, sh = (tid & 1) * 16;
  for (int k0 = 0; k0 < K; k0 += 32) {
    {
      const unsigned short* ap = &A[(size_t)(bm + sr) * K + k0 + sh];
      *(uint4*)&As[sr * 40 + sh] = *(const uint4*)ap;
      *(uint4*)&As[sr * 40 + sh + 8] = *(const uint4*)(ap + 8);
    }
    {
      const unsigned short* bp = &Bt[(size_t)(bn + sr) * K + k0 + sh];
      *(uint4*)&Bs[sr * 40 + sh] = *(const uint4*)bp;
      *(uint4*)&Bs[sr * 40 + sh + 8] = *(const uint4*)(bp + 8);
    }
    __syncthreads();
    bf16x8 af[4], bfr[4];
    #pragma unroll
    for (int mi = 0; mi < 4; mi++)
      af[mi] = *(const bf16x8*)&As[(wm + mi * 16 + r15) * 40 + q * 8];
    #pragma unroll
    for (int ni = 0; ni < 4; ni++)
      bfr[ni] = *(const bf16x8*)&Bs[(wn + ni * 16 + r15) * 40 + q * 8];
    #pragma unroll
    for (int mi = 0; mi < 4; mi++)
      #pragma unroll
      for (int ni = 0; ni < 4; ni++)
        acc[mi][ni] =
            __builtin_amdgcn_mfma_f32_16x16x32_bf16(af[mi], bfr[ni], acc[mi][ni], 0, 0, 0);
    __syncthreads();
  }
  float al = AXPY ? alphaPtr[0] : 0.f;
  #pragma unroll
  for (int mi = 0; mi < 4; mi++) {
    #pragma unroll
    for (int ni = 0; ni < 4; ni++) {
      int col = bn + wn + ni * 16 + r15;
      float bv = (bias && !AXPY) ? bias[col] : 0.f;
      #pragma unroll
      for (int v = 0; v < 4; v++) {
        int row = bm + wm + mi * 16 + q * 4 + v;
        float val = acc[mi][ni][v] + bv;
        if (RELU) val = fmaxf(val, 0.f);
        if (WF32) C[(size_t)row * N + col] = val;
        if (WBF16) Cb[(size_t)row * N + col] = f2bf(val);
        if (AXPY) {
          if (col < 64)
            C[(size_t)row * 64 + col] = R[(size_t)row * 64 + col] - al * val;
        }
      }
    }
  }
}

// tiled transpose-pack: dst[n*K + k] = bf16(src[k*N + n]); coalesced both sides
__global__ __launch_bounds__(256) void pack_transpose_bf16_kernel(
    const float* __restrict__ src, unsigned short* __restrict__ dst, int K, int N) {
  __shared__ unsigned short tile[64][65];
  int kb = blockIdx.x * 64, nb = blockIdx.y * 64;
  int tid = threadIdx.x;
  int tn = tid & 63, tk = tid >> 6;  // 4 rows per pass
  #pragma unroll
  for (int i = 0; i < 16; i++) {
    int k = tk + i * 4;
    tile[k][tn] = f2bf(src[(size_t)(kb + k) * N + nb + tn]);
  }
  __syncthreads();
  int tk2 = tid & 63, tn2 = tid >> 6;
  #pragma unroll
  for (int i = 0; i < 16; i++) {
    int n = tn2 + i * 4;
    dst[(size_t)(nb + n) * K + kb + tk2] = tile[tk2][n];
  }
}

__global__ void pack_bf16_kernel(const float* __restrict__ src, unsigned short* __restrict__ dst,
                                 int n) {
  int idx = blockIdx.x * 256 + threadIdx.x;
  if (idx < n) dst[idx] = f2bf(src[idx]);
}

// WxProjB[n][k] (n<128, k<1536) = n<64 ? bf16(wih[k*128 + n]) : 0
__global__ void pack_wxproj_kernel(const float* __restrict__ wih,
                                   unsigned short* __restrict__ dst) {
  int idx = blockIdx.x * 256 + threadIdx.x;  // 128*1536
  int k = idx % 1536, n = idx / 1536;
  float v = (n < 64) ? wih[(size_t)k * 128 + n] : 0.f;
  dst[idx] = f2bf(v);
}

__global__ void concat_qkv_bias_kernel(const float* __restrict__ bq, const float* __restrict__ bk,
                                       const float* __restrict__ bv, float* __restrict__ dst) {
  int l = blockIdx.y;
  int i = blockIdx.x * 256 + threadIdx.x;  // < 1536
  float v = (i < 512) ? bq[l * 512 + i]
                      : ((i < 1024) ? bk[l * 512 + i - 512] : bv[l * 512 + i - 1024]);
  dst[l * 1536 + i] = v;
}

// ---------------- MFMA attention: one block per (h,b) ----------------
__global__ __launch_bounds__(256) void attention_mfma_kernel(
    const unsigned short* __restrict__ qkv, unsigned short* __restrict__ attnO) {
  __shared__ __align__(16) unsigned short Ks[192 * 72];
  __shared__ __align__(16) unsigned short Vt[64 * 200];
  __shared__ __align__(16) float Ps[4][16 * 36];
  int h = blockIdx.x, b = blockIdx.y;
  int tid = threadIdx.x, wave = tid >> 6, lane = tid & 63;
  int m = lane & 15, q = lane >> 4;
  const unsigned short* Qg = qkv + (size_t)b * TT * 1536 + h * 64;
  const unsigned short* Kg = Qg + 512;
  const unsigned short* Vg = Qg + 1024;
  for (int idx = tid; idx < 192 * 8; idx += 256) {
    int s = idx >> 3, ch = (idx & 7) * 8;
    *(uint4*)&Ks[s * 72 + ch] = *(const uint4*)&Kg[(size_t)s * 1536 + ch];
  }
  for (int idx = tid; idx < 96 * 8; idx += 256) {
    int sp = idx >> 3, co = (idx & 7) * 8;
    uint4 v0 = *(const uint4*)&Vg[(size_t)(2 * sp) * 1536 + co];
    uint4 v1 = *(const uint4*)&Vg[(size_t)(2 * sp + 1) * 1536 + co];
    const unsigned short* e0 = (const unsigned short*)&v0;
    const unsigned short* e1 = (const unsigned short*)&v1;
    unsigned int* vtw = (unsigned int*)Vt;
    #pragma unroll
    for (int u = 0; u < 8; u++)
      vtw[(co + u) * 100 + sp] = (unsigned int)e0[u] | ((unsigned int)e1[u] << 16);
  }
  __syncthreads();
  float* ps = Ps[wave];
  for (int tile = wave; tile < 12; tile += 4) {
    int t0 = tile * 16;
    bf16x8 qf0 = *(const bf16x8*)&Qg[(size_t)(t0 + m) * 1536 + q * 8];
    bf16x8 qf1 = *(const bf16x8*)&Qg[(size_t)(t0 + m) * 1536 + 32 + q * 8];
    f32x4 S[12];
    #pragma unroll
    for (int nt = 0; nt < 12; nt++) {
      bf16x8 kf0 = *(const bf16x8*)&Ks[(nt * 16 + m) * 72 + q * 8];
      bf16x8 kf1 = *(const bf16x8*)&Ks[(nt * 16 + m) * 72 + 32 + q * 8];
      f32x4 a = {0.f, 0.f, 0.f, 0.f};
      a = __builtin_amdgcn_mfma_f32_16x16x32_bf16(qf0, kf0, a, 0, 0, 0);
      a = __builtin_amdgcn_mfma_f32_16x16x32_bf16(qf1, kf1, a, 0, 0, 0);
      S[nt] = a;
    }
    float mx[4] = {-1e30f, -1e30f, -1e30f, -1e30f};
    #pragma unroll
    for (int nt = 0; nt < 12; nt++)
      #pragma unroll
      for (int v = 0; v < 4; v++) {
        S[nt][v] *= 0.125f;
        mx[v] = fmaxf(mx[v], S[nt][v]);
      }
    #pragma unroll
    for (int d = 1; d < 16; d <<= 1) {
      #pragma unroll
      for (int v = 0; v < 4; v++) mx[v] = fmaxf(mx[v], __shfl_xor(mx[v], d));
    }
    float sm[4] = {0.f, 0.f, 0.f, 0.f};
    #pragma unroll
    for (int nt = 0; nt < 12; nt++)
      #pragma unroll
      for (int v = 0; v < 4; v++) {
        float e = __expf(S[nt][v] - mx[v]);
        S[nt][v] = e;
        sm[v] += e;
      }
    #pragma unroll
    for (int d = 1; d < 16; d <<= 1) {
      #pragma unroll
      for (int v = 0; v < 4; v++) sm[v] += __shfl_xor(sm[v], d);
    }
    float inv[4];
    #pragma unroll
    for (int v = 0; v < 4; v++) inv[v] = 1.f / sm[v];
    f32x4 o[4] = {};
    for (int kc = 0; kc < 6; kc++) {
      asm volatile("s_waitcnt lgkmcnt(0)" ::: "memory");
      #pragma unroll
      for (int half = 0; half < 2; half++) {
        int nt = 2 * kc + half;
        #pragma unroll
        for (int v = 0; v < 4; v++) ps[(q * 4 + v) * 36 + half * 16 + m] = S[nt][v];
      }
      asm volatile("s_waitcnt lgkmcnt(0)" ::: "memory");
      float4 p0 = *(const float4*)&ps[m * 36 + q * 8];
      float4 p1 = *(const float4*)&ps[m * 36 + q * 8 + 4];
      unsigned short tmp[8];
      tmp[0] = f2bf(p0.x); tmp[1] = f2bf(p0.y); tmp[2] = f2bf(p0.z); tmp[3] = f2bf(p0.w);
      tmp[4] = f2bf(p1.x); tmp[5] = f2bf(p1.y); tmp[6] = f2bf(p1.z); tmp[7] = f2bf(p1.w);
      bf16x8 pf = *(bf16x8*)tmp;
      #pragma unroll
      for (int nt2 = 0; nt2 < 4; nt2++) {
        bf16x8 vf = *(const bf16x8*)&Vt[(nt2 * 16 + m) * 200 + kc * 32 + q * 8];
        o[nt2] = __builtin_amdgcn_mfma_f32_16x16x32_bf16(pf, vf, o[nt2], 0, 0, 0);
      }
    }
    #pragma unroll
    for (int nt2 = 0; nt2 < 4; nt2++)
      #pragma unroll
      for (int v = 0; v < 4; v++) {
        size_t row = (size_t)b * TT + t0 + q * 4 + v;
        attnO[row * 512 + h * 64 + nt2 * 16 + m] = f2bf(o[nt2][v] * inv[v]);
      }
  }
}

// ---------------- layernorm with residual, in-place on x; bf16 copy ----------------
__global__ __launch_bounds__(256) void ln_residual_kernel(float* __restrict__ x,
                                                          const float* __restrict__ res,
                                                          const float* __restrict__ g,
                                                          const float* __restrict__ b,
                                                          unsigned short* __restrict__ xb) {
  int row = blockIdx.x, tid = threadIdx.x;
  __shared__ float red[256];
  float* xr = x + (size_t)row * DM;
  const float* rr = res + (size_t)row * DM;
  float v0 = xr[tid] + rr[tid];
  float v1 = xr[tid + 256] + rr[tid + 256];
  red[tid] = v0 + v1;
  __syncthreads();
  for (int s = 128; s > 0; s >>= 1) {
    if (tid < s) red[tid] += red[tid + s];
    __syncthreads();
  }
  float mu = red[0] * (1.f / DM);
  __syncthreads();
  float d0 = v0 - mu, d1 = v1 - mu;
  red[tid] = d0 * d0 + d1 * d1;
  __syncthreads();
  for (int s = 128; s > 0; s >>= 1) {
    if (tid < s) red[tid] += red[tid + s];
    __syncthreads();
  }
  float rstd = rsqrtf(red[0] * (1.f / DM) + 1e-5f);
  float o0 = d0 * rstd * g[tid] + b[tid];
  float o1 = d1 * rstd * g[tid + 256] + b[tid + 256];
  xr[tid] = o0;
  xr[tid + 256] = o1;
  xb[(size_t)row * DM + tid] = f2bf(o0);
  xb[(size_t)row * DM + tid + 256] = f2bf(o1);
}

__global__ void xcat_kernel(const float* __restrict__ corrupt, const float* __restrict__ cond,
                            unsigned short* __restrict__ xcatB) {
  int r = blockIdx.x, tid = threadIdx.x;  // 128 threads
  float v = (tid < 64) ? corrupt[(size_t)r * 64 + tid] : cond[(size_t)r * 64 + (tid - 64)];
  xcatB[(size_t)r * 128 + tid] = f2bf(v);
}

// ---------------- whh i8 pack, j-split (quad) layout ----------------
// whhJ entry: ((((quad*8+kh)*4+u)*3+g)*128 + jl)*16 + m ; k = kh*64+u*16+m, j = quad*128+jl
__global__ void pack_whh_q8_kernel(const float* __restrict__ whh, signed char* __restrict__ whhJ,
                                   float* __restrict__ sws) {
  int row = blockIdx.x;   // 0..1535 = g*512 + j
  int lane = threadIdx.x; // 64
  const float* src = whh + (size_t)row * 512;
  float mx = 0.f;
  for (int k = lane; k < 512; k += 64) mx = fmaxf(mx, fabsf(src[k]));
  for (int off = 32; off > 0; off >>= 1) mx = fmaxf(mx, __shfl_xor(mx, off));
  float inv = (mx > 0.f) ? 127.f / mx : 0.f;
  if (lane == 0) sws[row] = (mx / 127.f) * (8.f / 127.f);
  int g = row >> 9, j = row & 511;
  int quad = j >> 7, jl = j & 127;
  for (int k = lane; k < 512; k += 64) {
    int qv = (int)rintf(src[k] * inv);
    qv = qv < -127 ? -127 : (qv > 127 ? 127 : qv);
    int kh = k >> 6, u = (k >> 4) & 3, m = k & 15;
    whhJ[((size_t)((((quad * 8 + kh) * 4 + u) * 3 + g) * 128 + jl)) * 16 + m] = (signed char)qv;
  }
}

// ---------------- Langevin scan: 4 blocks per batch (j-split), reg-resident weights ----------------
// grid (BATCH, 4), 1024 thr = 16 waves. Each thread holds its 12 uint4 weight entries
// (192 B) in VGPRs for the whole scan — zero weight memory traffic after load.
// __launch_bounds__(1024,4): 4 waves/EU min -> VGPR cap 128 (need ~104).
__global__ __launch_bounds__(1024, 4) void langevin_scan_kernel(
    const float* __restrict__ gi_all, const float* __restrict__ hx0,
    const signed char* __restrict__ whhJ, const float* __restrict__ sws,
    const float* __restrict__ bhh, const float* __restrict__ score_w,
    unsigned short* __restrict__ dgiB, unsigned int* __restrict__ hqg,
    unsigned int* __restrict__ flags) {
  int b = blockIdx.x, quad = blockIdx.y;
  int tid = threadIdx.x;
  __shared__ float hloc[128];
  __shared__ __align__(16) unsigned int hq8[128];
  __shared__ int prI[1024], pzI[1024], pnI[1024];
  int jl = tid & 127, kh = tid >> 7;
  int j = quad * 128 + jl;
  float bhr = 0.f, bhz = 0.f, bhn = 0.f, sw = 0.f, swr = 0.f, swz = 0.f, swn = 0.f;
  if (tid < 128) {
    bhr = bhh[j]; bhz = bhh[512 + j]; bhn = bhh[1024 + j];
    sw = score_w[j] * COF;
    swr = sws[j]; swz = sws[512 + j]; swn = sws[1024 + j];
    hloc[tid] = hx0[(size_t)b * 512 + j];
    float4 hv = *(const float4*)&hx0[(size_t)b * 512 + tid * 4];
    float tmp[4] = {hv.x, hv.y, hv.z, hv.w};
    hq8[tid] = packq4(tmp);
  }
  __syncthreads();
  const uint4* wq = (const uint4*)whhJ + (size_t)quad * (8 * 4 * 3 * 128);
  const uint4* wk = wq + (size_t)kh * (4 * 3 * 128) + jl;
  // hoist the whole weight slice into registers (12 x uint4 = 48 VGPRs)
  uint4 wreg[12];
  #pragma unroll
  for (int u = 0; u < 4; u++) {
    wreg[u * 3 + 0] = wk[(u * 3 + 0) * 128];
    wreg[u * 3 + 1] = wk[(u * 3 + 1) * 128];
    wreg[u * 3 + 2] = wk[(u * 3 + 2) * 128];
  }
  for (int t = 0; t < TT; t++) {
    int ir = 0, iz = 0, in_ = 0;
    #pragma unroll
    for (int u = 0; u < 4; u++) {
      uint4 hqv = *(const uint4*)&hq8[kh * 16 + u * 4];
      ir = sd16(wreg[u * 3 + 0], hqv, ir);
      iz = sd16(wreg[u * 3 + 1], hqv, iz);
      in_ = sd16(wreg[u * 3 + 2], hqv, in_);
    }
    prI[tid] = ir; pzI[tid] = iz; pnI[tid] = in_;
    __syncthreads();
    if (tid < 128) {
      int sr_ = 0, sz_ = 0, sn_ = 0;
      #pragma unroll
      for (int kk = 0; kk < 8; kk++) {
        sr_ += prI[kk * 128 + jl];
        sz_ += pzI[kk * 128 + jl];
        sn_ += pnI[kk * 128 + jl];
      }
      float gr = (float)sr_ * swr, gz = (float)sz_ * swz, gn = (float)sn_ * swn;
      const float* gi = &gi_all[((size_t)b * TT + t) * 1536];
      float gir = gi[j], giz = gi[512 + j], gin = gi[1024 + j];
      float r = 1.f / (1.f + expf(-(gir + gr + bhr)));
      float z = 1.f / (1.f + expf(-(giz + gz + bhz)));
      float hnv = gn + bhn;
      float hj = hloc[jl];
      float n = tanhf(gin + r * hnv);
      float dinn = sw * (1.f - z) * (1.f - n * n);
      size_t drow = ((size_t)b * TT + t) * 1536;
      dgiB[drow + j] = f2bf(dinn * hnv * r * (1.f - r));
      dgiB[drow + 512 + j] = f2bf(sw * (hj - n) * z * (1.f - z));
      dgiB[drow + 1024 + j] = f2bf(dinn);
      hloc[jl] = (1.f - z) * n + z * hj;
    }
    __syncthreads();
    if (t + 1 < TT) {
      int slot = t & 1;
      if (tid < 32) {
        float tmp[4] = {hloc[tid * 4], hloc[tid * 4 + 1], hloc[tid * 4 + 2], hloc[tid * 4 + 3]};
        unsigned int v = packq4(tmp);
        hq8[quad * 32 + tid] = v;
        __hip_atomic_store(&hqg[(((size_t)slot * BATCH + b) * 4 + quad) * 32 + tid], v,
                           __ATOMIC_RELAXED, __HIP_MEMORY_SCOPE_AGENT);
      }
      if (tid == 0)
        __hip_atomic_store(&flags[b * 4 + quad], (unsigned)(t + 1), __ATOMIC_RELEASE,
                           __HIP_MEMORY_SCOPE_AGENT);
      if (tid < 3) {
        int oq = (quad + 1 + tid) & 3;
        while (__hip_atomic_load(&flags[b * 4 + oq], __ATOMIC_ACQUIRE,
                                 __HIP_MEMORY_SCOPE_AGENT) < (unsigned)(t + 1)) {
          __builtin_amdgcn_s_sleep(4);
        }
      }
      __syncthreads();
      if (tid < 96) {
        int o = tid >> 5, w = tid & 31;
        int oq = (quad + 1 + o) & 3;
        hq8[oq * 32 + w] =
            __hip_atomic_load(&hqg[(((size_t)slot * BATCH + b) * 4 + oq) * 32 + w],
                              __ATOMIC_RELAXED, __HIP_MEMORY_SCOPE_AGENT);
      }
      __syncthreads();
    }
  }
}

// denorm + write d_out + loss partial
__global__ __launch_bounds__(256) void denorm_loss_kernel(
    const float* __restrict__ outb, const float* __restrict__ stdev,
    const float* __restrict__ means, const float* __restrict__ y, float* __restrict__ dout,
    float* __restrict__ loss) {
  int idx = blockIdx.x * 256 + threadIdx.x;
  int tid = threadIdx.x;
  int c = idx & 63;
  int bt = idx >> 6;
  int t = bt % TT, b = bt / TT;
  float od = outb[idx] * stdev[b * CIN + c] + means[b * CIN + c];
  dout[idx] = od;
  float diff = fabsf(od - y[((size_t)b * 240 + 48 + t) * CIN + c]);
  __shared__ float red[256];
  red[tid] = diff;
  __syncthreads();
  for (int s = 128; s > 0; s >>= 1) {
    if (tid < s) red[tid] += red[tid + s];
    __syncthreads();
  }
  if (tid == 0) atomicAdd(loss, red[0]);
}

// ---------------- host launch ----------------
extern "C" void kernel_launch(void* const* d_in, const int* in_sizes, int n_in, void* d_out,
                              int out_size, void* d_ws, size_t ws_size, hipStream_t stream) {
  const float* x_enc = (const float*)d_in[0];
  const float* batch_y = (const float*)d_in[2];
  const float* y_mark = (const float*)d_in[3];
  const float* hx_init = (const float*)d_in[4];
  const float* conv_w = (const float*)d_in[5];
  const float* tf_w = (const float*)d_in[6];
  const float* Wq = (const float*)d_in[7];
  const float* Wk = (const float*)d_in[8];
  const float* Wv = (const float*)d_in[9];
  const float* Wo = (const float*)d_in[10];
  const float* bq = (const float*)d_in[11];
  const float* bk = (const float*)d_in[12];
  const float* bv = (const float*)d_in[13];
  const float* bo = (const float*)d_in[14];
  const float* ln1_g = (const float*)d_in[15];
  const float* ln1_b = (const float*)d_in[16];
  const float* W1 = (const float*)d_in[17];
  const float* b1 = (const float*)d_in[18];
  const float* W2 = (const float*)d_in[19];
  const float* b2 = (const float*)d_in[20];
  const float* ln2_g = (const float*)d_in[21];
  const float* ln2_b = (const float*)d_in[22];
  const float* pl1_w = (const float*)d_in[23];
  const float* pl1_b = (const float*)d_in[24];
  const float* pl2_w = (const float*)d_in[25];
  const float* pl2_b = (const float*)d_in[26];
  const float* proj_w = (const float*)d_in[27];
  const float* proj_b = (const float*)d_in[28];
  const float* gru_wih = (const float*)d_in[29];
  const float* gru_whh = (const float*)d_in[30];
  const float* gru_bih = (const float*)d_in[31];
  const float* gru_bhh = (const float*)d_in[32];
  const float* score_w = (const float*)d_in[33];
  const float* alpha = (const float*)d_in[34];
  float* dout = (float*)d_out;

  float* W = (float*)d_ws;
  size_t off = 0;
  float* means = W + off;   off += 2048;
  float* stdev = W + off;   off += 2048;
  float* lossacc = W + off; off += 64;
  float* preA = W + off;    off += (size_t)OUTN;
  float* outA = W + off;    off += (size_t)OUTN;
  float* outB = W + off;    off += (size_t)OUTN;
  float* corrupt = W + off; off += (size_t)OUTN;
  float* cond = W + off;    off += (size_t)OUTN;
  signed char* whhJ = (signed char*)(W + off); off += 786432 / 4;
  float* sws = W + off;     off += 1536;
  unsigned int* flagsU = (unsigned int*)(W + off); off += 128;
  unsigned int* hqg = (unsigned int*)(W + off);    off += 2 * BATCH * 4 * 32;
  float* emb = W + off;     off += (size_t)BATCH * TT * DM;
  float* Kb = W + off;      off += (size_t)BATCH * TT * DM;
  float* gi_all = W + off;  off += (size_t)BATCH * TT * 1536;
  unsigned short* embB = (unsigned short*)(W + off);  off += (size_t)BATCH * TT * DM / 2;
  unsigned short* qkvB = (unsigned short*)(W + off);  off += (size_t)BATCH * TT * 1536 / 2;
  unsigned short* attnOB = (unsigned short*)(W + off); off += (size_t)BATCH * TT * DM / 2;
  unsigned short* FFbB = (unsigned short*)(W + off);  off += (size_t)BATCH * TT * DFF / 2;
  unsigned short* xcatB = (unsigned short*)(W + off); off += (size_t)BATCH * TT * 128 / 2;
  float* bqkv = W + off;    off += 2 * 1536;
  unsigned short* WxProjB = (unsigned short*)(W + off); off += (size_t)128 * 1536 / 2;
  unsigned short* wT = (unsigned short*)(W + off);
  const size_t SQ = (size_t)DM * DM;
  const size_t SFF = (size_t)DM * DFF;
  const size_t LAYER = 4 * SQ + 2 * SFF;
  unsigned short* wihB = wT + 2 * LAYER;
  off += (2 * LAYER + (size_t)1536 * 128) / 2 + 64;
  unsigned short* dgiB = qkvB;  // alias: qkvB dead after attention, reused for dgi

  const int M = BATCH * TT;  // 6144

  zero_loss_kernel<<<1, 64, 0, stream>>>(lossacc);
  stats_kernel<<<BATCH, 64, 0, stream>>>(x_enc, means, stdev);
  pl1_kernel<<<dim3(TT, BATCH), 64, 0, stream>>>(x_enc, means, stdev, pl1_w, pl1_b, preA);
  pack_whh_q8_kernel<<<1536, 64, 0, stream>>>(gru_whh, whhJ, sws);
  pack_wxproj_kernel<<<(128 * 1536) / 256, 256, 0, stream>>>(gru_wih, WxProjB);
  concat_qkv_bias_kernel<<<dim3(6, 2), 256, 0, stream>>>(bq, bk, bv, bqkv);
  for (int l = 0; l < 2; l++) {
    unsigned short* base = wT + (size_t)l * LAYER;
    pack_transpose_bf16_kernel<<<dim3(8, 8), 256, 0, stream>>>(Wq + (size_t)l * SQ, base, DM, DM);
    pack_transpose_bf16_kernel<<<dim3(8, 8), 256, 0, stream>>>(Wk + (size_t)l * SQ, base + SQ, DM, DM);
    pack_transpose_bf16_kernel<<<dim3(8, 8), 256, 0, stream>>>(Wv + (size_t)l * SQ, base + 2 * SQ, DM, DM);
    pack_transpose_bf16_kernel<<<dim3(8, 8), 256, 0, stream>>>(Wo + (size_t)l * SQ, base + 3 * SQ, DM, DM);
    pack_transpose_bf16_kernel<<<dim3(8, 32), 256, 0, stream>>>(W1 + (size_t)l * SFF, base + 4 * SQ, DM, DFF);
    pack_transpose_bf16_kernel<<<dim3(32, 8), 256, 0, stream>>>(W2 + (size_t)l * SFF, base + 4 * SQ + SFF, DFF, DM);
  }
  pack_bf16_kernel<<<(1536 * 128) / 256, 256, 0, stream>>>(gru_wih, wihB, 1536 * 128);

  const float* pre = preA;
  float* outs[2] = {outA, outB};
  for (int s = 0; s < 2; s++) {
    pl2_kernel<<<dim3(TT, BATCH), 64, 0, stream>>>(pre, pl2_w, pl2_b, corrupt);
    embed_kernel<<<dim3(TT, BATCH), DM, 0, stream>>>(corrupt, y_mark, conv_w, tf_w, emb, embB);
    for (int l = 0; l < 2; l++) {
      unsigned short* base = wT + (size_t)l * LAYER;
      gemm_bf16_kernel<0, 0, 1, 0><<<dim3(1536 / 128, M / 128), 256, 0, stream>>>(
          embB, base, bqkv + l * 1536, nullptr, qkvB, nullptr, nullptr, M, 1536, DM);
      attention_mfma_kernel<<<dim3(NH, BATCH), 256, 0, stream>>>(qkvB, attnOB);
      gemm_bf16_kernel<0, 1, 0, 0><<<dim3(DM / 128, M / 128), 256, 0, stream>>>(
          attnOB, base + 3 * SQ, bo + l * DM, Kb, nullptr, nullptr, nullptr, M, DM, DM);
      ln_residual_kernel<<<M, 256, 0, stream>>>(emb, Kb, ln1_g + l * DM, ln1_b + l * DM, embB);
      gemm_bf16_kernel<1, 0, 1, 0><<<dim3(DFF / 128, M / 128), 256, 0, stream>>>(
          embB, base + 4 * SQ, b1 + l * DFF, nullptr, FFbB, nullptr, nullptr, M, DFF, DM);
      gemm_bf16_kernel<0, 1, 0, 0><<<dim3(DM / 128, M / 128), 256, 0, stream>>>(
          FFbB, base + 4 * SQ + SFF, b2 + l * DM, Kb, nullptr, nullptr, nullptr, M, DM, DFF);
      ln_residual_kernel<<<M, 256, 0, stream>>>(emb, Kb, ln2_g + l * DM, ln2_b + l * DM, embB);
    }
    gemm_kernel<1, 0><<<dim3(CIN / 64, M / 64), 256, 0, stream>>>(
        emb, proj_w, proj_b, cond, M, CIN, DM);
    xcat_kernel<<<M, 128, 0, stream>>>(corrupt, cond, xcatB);
    gemm_bf16_kernel<0, 1, 0, 0><<<dim3(1536 / 128, M / 128), 256, 0, stream>>>(
        xcatB, wihB, gru_bih, gi_all, nullptr, nullptr, nullptr, M, 1536, 128);
    zero_flags_kernel<<<1, 128, 0, stream>>>(flagsU);
    langevin_scan_kernel<<<dim3(BATCH, 4), 1024, 0, stream>>>(
        gi_all, hx_init + (size_t)s * BATCH * DM, whhJ, sws, gru_bhh, score_w, dgiB, hqg,
        flagsU);
    // out = xi - alpha * dgi @ Wx^T   (AXPY epilogue)
    gemm_bf16_kernel<0, 0, 0, 1><<<dim3(1, M / 128), 256, 0, stream>>>(
        dgiB, WxProjB, nullptr, outs[s], nullptr, corrupt, alpha, M, 128, 1536);
    denorm_loss_kernel<<<OUTN / 256, 256, 0, stream>>>(outs[s], stdev, means, batch_y, dout,
                                                       lossacc);
    pre = outs[s];
  }
  finalize_kernel<<<1, 1, 0, stream>>>(dout, lossacc);
}